// Round 3
// baseline (736.042 us; speedup 1.0000x reference)
//
#include <hip/hip_runtime.h>
#include <stdint.h>

typedef unsigned long long u64;

#define BB 8
#define NN 200000
#define CLS 20
#define K_PRE 500
#define MAXDET 300
#define SCORE_TH 0.05f
#define NMS_THR 0.5f

#define NBINS 512
#define CAND_CAP 4096

// fast path: fixed conservative collect threshold (uniform scores -> ~842/class >> 500)
// exactness for arbitrary inputs preserved by device-side fallback chain below.
#define T_COL 0.996f

// fast collect geometry: 8 independent loads per thread for MLP
#define CB_THREADS 256
#define CB_BLOCKS 512
#define IMG_F4 (NN * CLS / 4)               // 1,000,000 float4 per image
#define CB_STRIDE (CB_BLOCKS * CB_THREADS)  // 131072

// fallback grid (old histogram path; no-op in practice)
#define SLABS 25
#define NPER (NN / SLABS)       // 8000
#define FPB (NPER * CLS)        // 160000

static constexpr float BINSCALE = (float)NBINS / 0.95f;

// ws layout (bytes)
#define HIST_OFF 0            // 8*20*512*4 = 327680
#define THR_OFF  327680       // 640
#define CCNT_OFF 328320       // 640
#define KSEL_OFF 328960       // 640
#define ZERO_BYTES 329600
#define CAND_OFF 329600       // 160*4096*8 = 5242880
#define CSELK_OFF 5572480     // 160*300*8 = 384000
#define CSELA_OFF 5956480     // 160*300*4 = 192000

__device__ __forceinline__ int score_bin(float s) {
  int b = (int)((s - SCORE_TH) * BINSCALE);
  return b < 0 ? 0 : (b > NBINS - 1 ? NBINS - 1 : b);
}

__device__ __forceinline__ u64 shflx64(u64 v, int mask) {
  int hi = __shfl_xor((int)(unsigned)(v >> 32), mask, 64);
  int lo = __shfl_xor((int)(unsigned)(v & 0xFFFFFFFFu), mask, 64);
  return ((u64)(unsigned)hi << 32) | (unsigned)lo;
}

// ---- fast path: single streaming pass, 8-deep MLP, fixed threshold ----
__global__ __launch_bounds__(256) void k_collect1(const float* __restrict__ cls,
                                                  int* __restrict__ ccount, u64* __restrict__ cand) {
  int b = blockIdx.y;
  int t0 = blockIdx.x * CB_THREADS + threadIdx.x;  // 0..131071
  const float4* base = (const float4*)(cls + (size_t)b * NN * CLS);
  float4 v[8];
#pragma unroll
  for (int k = 0; k < 7; ++k) v[k] = base[t0 + k * CB_STRIDE];  // always in range
  v[7] = make_float4(0.f, 0.f, 0.f, 0.f);
  if (t0 + 7 * CB_STRIDE < IMG_F4) v[7] = base[t0 + 7 * CB_STRIDE];
  float mx = 0.f;
#pragma unroll
  for (int k = 0; k < 8; ++k)
    mx = fmaxf(mx, fmaxf(fmaxf(v[k].x, v[k].y), fmaxf(v[k].z, v[k].w)));
  if (mx > T_COL) {
#pragma unroll
    for (int k = 0; k < 8; ++k) {
      float vv[4] = {v[k].x, v[k].y, v[k].z, v[k].w};
#pragma unroll
      for (int e = 0; e < 4; ++e) {
        float s = vv[e];
        if (s > T_COL) {
          int g = (t0 + k * CB_STRIDE) * 4 + e;   // in-image float index
          int c = g % CLS;
          int anchor = g / CLS;
          int pos = atomicAdd(&ccount[b * CLS + c], 1);
          if (pos < CAND_CAP)
            cand[((size_t)(b * CLS + c)) * CAND_CAP + pos] =
                ((u64)__float_as_uint(s) << 32) | (u64)(0xFFFFFFFFu - (unsigned)anchor);
        }
      }
    }
  }
}

// ---- fallback chain (exactness for arbitrary inputs; no-ops for this data) ----
__global__ __launch_bounds__(256) void k_fb_hist(const float* __restrict__ cls,
                                                 const int* __restrict__ ccount, int* __restrict__ hist) {
  int slab = blockIdx.x, b = blockIdx.y;
  bool need = false;
  for (int c = threadIdx.x; c < CLS; c += 256) {
    int cnt = ccount[b * CLS + c];
    if (cnt < K_PRE || cnt > CAND_CAP) need = true;
  }
  __shared__ int sneed;
  if (threadIdx.x == 0) sneed = 0;
  __syncthreads();
  if (__ballot(need)) if ((threadIdx.x & 63) == 0) atomicOr(&sneed, 1);
  __syncthreads();
  if (!sneed) return;

  __shared__ int lh[CLS * NBINS];  // 40KB
  for (int i = threadIdx.x; i < CLS * NBINS; i += 256) lh[i] = 0;
  __syncthreads();
  const float4* base = (const float4*)(cls + ((size_t)b * NN + (size_t)slab * NPER) * CLS);
  for (int t = threadIdx.x; t < FPB / 4; t += 256) {
    float4 v = base[t];
    int i0 = t * 4;
    float vv[4] = {v.x, v.y, v.z, v.w};
#pragma unroll
    for (int k = 0; k < 4; ++k) {
      float s = vv[k];
      if (s > SCORE_TH) {
        int c = (i0 + k) % CLS;
        atomicAdd(&lh[c * NBINS + score_bin(s)], 1);
      }
    }
  }
  __syncthreads();
  int* gh = hist + (size_t)b * CLS * NBINS;
  for (int i = threadIdx.x; i < CLS * NBINS; i += 256) {
    int v = lh[i];
    if (v) atomicAdd(&gh[i], v);
  }
}

__global__ void k_fb_thr(const int* __restrict__ hist, int* __restrict__ thr, int* __restrict__ ccount) {
  int t = blockIdx.x * blockDim.x + threadIdx.x;
  if (t >= BB * CLS) return;
  int cnt = ccount[t];
  if (cnt >= K_PRE && cnt <= CAND_CAP) { thr[t] = NBINS; return; }
  const int* h = hist + (size_t)t * NBINS;
  int sum = 0, bin = 0;
  for (int i = NBINS - 1; i >= 0; --i) {
    sum += h[i];
    if (sum >= K_PRE) { bin = i; break; }
  }
  thr[t] = bin;
  ccount[t] = 0;
}

__global__ __launch_bounds__(256) void k_fb_collect(const float* __restrict__ cls, const int* __restrict__ thr,
                                                    int* __restrict__ ccount, u64* __restrict__ cand) {
  __shared__ int lthr[CLS];
  __shared__ int sneed;
  int slab = blockIdx.x, b = blockIdx.y;
  if (threadIdx.x == 0) sneed = 0;
  __syncthreads();
  if (threadIdx.x < CLS) {
    int tv = thr[b * CLS + threadIdx.x];
    lthr[threadIdx.x] = tv;
    if (tv < NBINS) atomicOr(&sneed, 1);
  }
  __syncthreads();
  if (!sneed) return;
  const float4* base = (const float4*)(cls + ((size_t)b * NN + (size_t)slab * NPER) * CLS);
  int n0 = slab * NPER;
  for (int t = threadIdx.x; t < FPB / 4; t += 256) {
    float4 v = base[t];
    int i0 = t * 4;
    float vv[4] = {v.x, v.y, v.z, v.w};
#pragma unroll
    for (int k = 0; k < 4; ++k) {
      float s = vv[k];
      if (s > SCORE_TH) {
        int idx = i0 + k;
        int c = idx % CLS;
        if (score_bin(s) >= lthr[c]) {
          int pos = atomicAdd(&ccount[b * CLS + c], 1);
          if (pos < CAND_CAP) {
            int anchor = n0 + idx / CLS;
            cand[((size_t)(b * CLS + c)) * CAND_CAP + pos] =
                ((u64)__float_as_uint(s) << 32) | (u64)(0xFFFFFFFFu - (unsigned)anchor);
          }
        }
      }
    }
  }
}

// ---- per-(b,c): exact top-500, greedy NMS, per-class cap, compact ----
// fast sort path: 1024-thread in-register bitonic, shfl_xor for j<64 (45 of 55
// rounds barrier-free), LDS exchange only for j>=64 (10 rounds).
__global__ __launch_bounds__(1024) void k_nms(const float* __restrict__ boxes, const int* __restrict__ ccount,
                                              const u64* __restrict__ cand, u64* __restrict__ cselk,
                                              int* __restrict__ csela, int* __restrict__ ksel) {
  __shared__ u64 keys[CAND_CAP];  // 32KB; holds sorted keys, then reused as sup[500][8]
  __shared__ float sx1[K_PRE], sy1[K_PRE], sx2[K_PRE], sy2[K_PRE], sar[K_PRE], ssc[K_PRE];
  __shared__ int sanchor[K_PRE];
  __shared__ u64 keepw[8];
  int bc = blockIdx.x;
  int b = bc / CLS, c = bc % CLS;
  int tid = threadIdx.x;
  int m = ccount[bc]; if (m > CAND_CAP) m = CAND_CAP;

  if (m <= 1024) {
    // in-register bitonic, descending
    u64 key = (tid < m) ? cand[(size_t)bc * CAND_CAP + tid] : 0ULL;
    for (int k2 = 2; k2 <= 1024; k2 <<= 1) {
      for (int j = k2 >> 1; j > 0; j >>= 1) {
        u64 other;
        if (j >= 64) {
          keys[tid] = key; __syncthreads();
          other = keys[tid ^ j]; __syncthreads();
        } else {
          other = shflx64(key, j);
        }
        bool keepmax = (((tid & k2) == 0) == ((tid & j) == 0));
        key = keepmax ? (key >= other ? key : other) : (key <= other ? key : other);
      }
    }
    keys[tid] = key;
    __syncthreads();
  } else {
    // slow exact path (never taken for this data): LDS bitonic up to 4096
    int nsort = 2048; while (nsort < m) nsort <<= 1;
    for (int i = tid; i < nsort; i += 1024) keys[i] = (i < m) ? cand[(size_t)bc * CAND_CAP + i] : 0ULL;
    __syncthreads();
    for (int k2 = 2; k2 <= nsort; k2 <<= 1) {
      for (int j = k2 >> 1; j > 0; j >>= 1) {
        for (int i = tid; i < nsort; i += 1024) {
          int ij = i ^ j;
          if (ij > i) {
            u64 a = keys[i], bv = keys[ij];
            bool up = ((i & k2) == 0);
            if (up ? (a < bv) : (a > bv)) { keys[i] = bv; keys[ij] = a; }
          }
        }
        __syncthreads();
      }
    }
  }

  // extract top-500 fragments
  bool val = false;
  if (tid < K_PRE) {
    u64 key = keys[tid];
    float sc = __uint_as_float((unsigned)(key >> 32));
    unsigned anchor = 0xFFFFFFFFu - (unsigned)(key & 0xFFFFFFFFu);
    val = sc > SCORE_TH;
    if (!val || anchor >= NN) anchor = 0;
    float4 bx = *(const float4*)(boxes + ((size_t)b * NN + anchor) * 4);
    sx1[tid] = bx.x; sy1[tid] = bx.y; sx2[tid] = bx.z; sy2[tid] = bx.w;
    sar[tid] = fmaxf(bx.z - bx.x, 0.0f) * fmaxf(bx.w - bx.y, 0.0f);
    ssc[tid] = sc; sanchor[tid] = (int)anchor;
  }
  u64 bm = __ballot(val);
  if ((tid & 63) == 0 && tid < 512) keepw[tid >> 6] = bm;
  __syncthreads();
  // zero + build suppression bitmatrix (iou>0.5 & j>i), exact reference fp32 arithmetic
  for (int i = tid; i < K_PRE * 8; i += 1024) keys[i] = 0ULL;
  __syncthreads();
  for (int tt = tid; tt < K_PRE * 8; tt += 1024) {
    int i = tt >> 3, w = tt & 7;
    float xi1 = sx1[i], yi1 = sy1[i], xi2 = sx2[i], yi2 = sy2[i], ai = sar[i];
    int j0 = w << 6;
    int jend = (j0 + 64 < K_PRE) ? j0 + 64 : K_PRE;
    int jst = (j0 > i + 1) ? j0 : i + 1;
    u64 word = 0;
    for (int j = jst; j < jend; ++j) {
      float iw = fmaxf(fminf(xi2, sx2[j]) - fmaxf(xi1, sx1[j]), 0.0f);
      float ih = fmaxf(fminf(yi2, sy2[j]) - fmaxf(yi1, sy1[j]), 0.0f);
      float inter = iw * ih;
      float denom = fmaxf(ai + sar[j] - inter, 1e-8f);
      if (inter / denom > NMS_THR) word |= 1ULL << (j - j0);
    }
    keys[i * 8 + w] = word;
  }
  __syncthreads();
  // greedy sweep: lanes 0-7 of wave 0 own the 8 keep words; row i+1 prefetched
  if (tid < 64) {
    u64 kw = (tid < 8) ? keepw[tid] : 0ULL;
    u64 row = (tid < 8) ? keys[tid] : 0ULL;  // row 0
    for (int i = 0; i < K_PRE; ++i) {
      u64 nrow = (tid < 8 && i + 1 < K_PRE) ? keys[(i + 1) * 8 + tid] : 0ULL;
      int owner = i >> 6;
      unsigned bit = (unsigned)((kw >> (i & 63)) & 1ULL);
      bit = (unsigned)__shfl((int)bit, owner, 64);
      u64 msk = 0ULL - (u64)bit;
      kw &= ~(row & msk);
      row = nrow;
    }
    if (tid < 8) keepw[tid] = kw;
    int cnt = (tid < 8) ? __popcll(kw) : 0;
    cnt += __shfl_xor(cnt, 1, 64);
    cnt += __shfl_xor(cnt, 2, 64);
    cnt += __shfl_xor(cnt, 4, 64);
    if (tid == 0) ksel[bc] = cnt > MAXDET ? MAXDET : cnt;
  }
  __syncthreads();
  // rank (cumsum-1) and compact survivors with rank < 300
  if (tid < K_PRE) {
    int w = tid >> 6, bpos = tid & 63;
    u64 kw = keepw[w];
    if ((kw >> bpos) & 1ULL) {
      int rank = 0;
      for (int ww = 0; ww < w; ++ww) rank += __popcll(keepw[ww]);
      rank += __popcll(kw & ((1ULL << bpos) - 1ULL));
      if (rank < MAXDET) {
        unsigned flat = (unsigned)(c * K_PRE + tid);  // tie-break: lower flat index first
        cselk[(size_t)bc * MAXDET + rank] = ((u64)__float_as_uint(ssc[tid]) << 32) | (u64)(0xFFFFFFFFu - flat);
        csela[(size_t)bc * MAXDET + rank] = sanchor[tid];
      }
    }
  }
}

// ---- per-image: 20-way tournament merge of sorted survivor lists -> global top-300 ----
__global__ __launch_bounds__(256) void k_out(const float* __restrict__ boxes, const u64* __restrict__ cselk,
                                             const int* __restrict__ csela, const int* __restrict__ ksel,
                                             float* __restrict__ out) {
  __shared__ u64 skey[CLS][MAXDET];  // 48KB
  __shared__ int skc[CLS];
  __shared__ int winc[MAXDET];
  __shared__ float winsc[MAXDET];
  int b = blockIdx.x, tid = threadIdx.x;
  if (tid < CLS) skc[tid] = ksel[b * CLS + tid];
  __syncthreads();
  for (int t = tid; t < CLS * MAXDET; t += 256) {
    int c = t / MAXDET, p = t % MAXDET;
    skey[c][p] = (p < skc[c]) ? cselk[(size_t)(b * CLS + c) * MAXDET + p] : 0ULL;
  }
  __syncthreads();
  if (tid < 64) {
    int lane = tid;
    u64 cur = 0, nxt = 0; int p = 0, kc = 0;
    if (lane < CLS) {
      kc = skc[lane];
      cur = kc > 0 ? skey[lane][0] : 0ULL;
      nxt = kc > 1 ? skey[lane][1] : 0ULL;
    }
    for (int i = 0; i < MAXDET; ++i) {
      u64 mx = cur;
#pragma unroll
      for (int off = 16; off >= 1; off >>= 1) {  // heads live in lanes 0..19 -> 32-lane reduce
        unsigned hi = __shfl_xor((int)(unsigned)(mx >> 32), off, 32);
        unsigned lo = __shfl_xor((int)(unsigned)(mx & 0xFFFFFFFFu), off, 32);
        u64 o = ((u64)hi << 32) | lo;
        if (o > mx) mx = o;
      }
      if (mx != 0ULL && cur == mx) {  // keys unique -> exactly one winner
        winc[i] = (lane << 16) | p;
        winsc[i] = __uint_as_float((unsigned)(mx >> 32));
        ++p;
        cur = nxt;
        nxt = (p + 1 < kc) ? skey[lane][p + 1] : 0ULL;
      }
      if (mx == 0ULL && lane == 0) winc[i] = -1;
    }
  }
  __syncthreads();
  for (int i = tid; i < MAXDET; i += 256) {
    int wc = winc[i];
    float4 bx; float sc, lb;
    if (wc < 0) {
      bx = make_float4(-1.f, -1.f, -1.f, -1.f); sc = -1.f; lb = -1.f;
    } else {
      int c = wc >> 16, p = wc & 0xFFFF;
      int anchor = csela[(size_t)(b * CLS + c) * MAXDET + p];
      bx = *(const float4*)(boxes + ((size_t)b * NN + anchor) * 4);
      sc = winsc[i];
      lb = (float)(c - 1);  // reference: out_labels = fl - 1
    }
    *(float4*)(out + ((size_t)b * MAXDET + i) * 4) = bx;
    out[BB * MAXDET * 4 + b * MAXDET + i] = sc;
    out[BB * MAXDET * 4 + BB * MAXDET + b * MAXDET + i] = lb;
  }
}

extern "C" void kernel_launch(void* const* d_in, const int* in_sizes, int n_in,
                              void* d_out, int out_size, void* d_ws, size_t ws_size,
                              hipStream_t stream) {
  (void)in_sizes; (void)n_in; (void)out_size; (void)ws_size;
  const float* boxes = (const float*)d_in[0];
  const float* cls = (const float*)d_in[1];
  float* out = (float*)d_out;
  char* ws = (char*)d_ws;
  int* hist   = (int*)(ws + HIST_OFF);
  int* thr    = (int*)(ws + THR_OFF);
  int* ccount = (int*)(ws + CCNT_OFF);
  int* ksel   = (int*)(ws + KSEL_OFF);
  u64* cand   = (u64*)(ws + CAND_OFF);
  u64* cselk  = (u64*)(ws + CSELK_OFF);
  int* csela  = (int*)(ws + CSELA_OFF);

  hipMemsetAsync(ws, 0, ZERO_BYTES, stream);
  k_collect1<<<dim3(CB_BLOCKS, BB), CB_THREADS, 0, stream>>>(cls, ccount, cand);
  k_fb_hist<<<dim3(SLABS, BB), 256, 0, stream>>>(cls, ccount, hist);
  k_fb_thr<<<1, 256, 0, stream>>>(hist, thr, ccount);
  k_fb_collect<<<dim3(SLABS, BB), 256, 0, stream>>>(cls, thr, ccount, cand);
  k_nms<<<BB * CLS, 1024, 0, stream>>>(boxes, ccount, cand, cselk, csela, ksel);
  k_out<<<BB, 256, 0, stream>>>(boxes, cselk, csela, ksel, out);
}

// Round 4
// 272.257 us; speedup vs baseline: 2.7035x; 2.7035x over previous
//
#include <hip/hip_runtime.h>
#include <stdint.h>

typedef unsigned long long u64;

#define BB 8
#define NN 200000
#define CLS 20
#define K_PRE 500
#define MAXDET 300
#define SCORE_TH 0.05f
#define NMS_THR 0.5f

#define NBINS 512
#define CAND_CAP 4096

// fast path: fixed conservative collect threshold (uniform scores -> ~842/class >> 500)
// exactness for arbitrary inputs preserved by the histogram fallback chain.
#define T_COL 0.996f

// collect geometry: 128 blocks/image, 256 thr, 8 named loads in flight, contiguous 32KB chunks
#define CBLK 128
#define CTHR 256
#define IMG_F4 1000000            // NN*CLS/4 float4 per image
#define ITERS 4                   // 4 * 8*256 = 8192 float4 per block
#define BCAP 32                   // per block-class staging capacity (lambda ~6.6)

// fallback grid (old histogram path; no-op in practice)
#define SLABS 25
#define NPER (NN / SLABS)
#define FPB (NPER * CLS)

static constexpr float BINSCALE = (float)NBINS / 0.95f;

// ws layout (bytes)
#define HIST_OFF 0              // 8*20*512*4 = 327680
#define THR_OFF  327680         // 640
#define CCNT_OFF 328320         // 640
#define KSEL_OFF 328960         // 640
#define ZERO_BYTES 329600
#define CAND_OFF 329600         // 160*4096*8 = 5242880
#define CSELK_OFF 5572480       // 160*300*8 = 384000
#define CSELA_OFF 5956480       // 160*300*4 = 192000
#define BCNT_OFF 6148480        // 1024*20*4 = 81920
#define BDATA_OFF 6230400       // 1024*20*32*8 = 5242880  (end 11473280)

__device__ __forceinline__ int score_bin(float s) {
  int b = (int)((s - SCORE_TH) * BINSCALE);
  return b < 0 ? 0 : (b > NBINS - 1 ? NBINS - 1 : b);
}

__device__ __forceinline__ u64 shflx64(u64 v, int mask) {
  int hi = __shfl_xor((int)(unsigned)(v >> 32), mask, 64);
  int lo = __shfl_xor((int)(unsigned)(v & 0xFFFFFFFFu), mask, 64);
  return ((u64)(unsigned)hi << 32) | (unsigned)lo;
}

// ---- streaming pass: zero global atomics, LDS staging, per-block output region ----
__global__ __launch_bounds__(256) void k_collect(const float* __restrict__ cls,
                                                 int* __restrict__ bcnt, u64* __restrict__ bdata) {
  __shared__ u64 ldata[CLS][BCAP];   // 5KB
  __shared__ int lcnt[CLS];
  int tid = threadIdx.x;
  if (tid < CLS) lcnt[tid] = 0;
  __syncthreads();
  int blk = blockIdx.x, b = blockIdx.y;
  const float4* p = (const float4*)(cls + (size_t)b * IMG_F4 * 4);
  int base0 = blk * (ITERS * 8 * CTHR);
  bool full = (base0 + ITERS * 8 * CTHR) <= IMG_F4;

#define PROC(v, fidx) { \
    float m4_ = fmaxf(fmaxf((v).x, (v).y), fmaxf((v).z, (v).w)); \
    if (m4_ > T_COL) { \
      float vv_[4] = {(v).x, (v).y, (v).z, (v).w}; \
      _Pragma("unroll") \
      for (int e_ = 0; e_ < 4; ++e_) { \
        if (vv_[e_] > T_COL) { \
          int g_ = (fidx) * 4 + e_; \
          int c_ = g_ % CLS, a_ = g_ / CLS; \
          int li_ = atomicAdd(&lcnt[c_], 1); \
          if (li_ < BCAP) \
            ldata[c_][li_] = ((u64)__float_as_uint(vv_[e_]) << 32) | (u64)(0xFFFFFFFFu - (unsigned)a_); \
        } \
      } \
    } }

  for (int it = 0; it < ITERS; ++it) {
    int i0 = base0 + it * (8 * CTHR) + tid;
    if (full) {
      float4 v0 = p[i0];
      float4 v1 = p[i0 + 1 * CTHR];
      float4 v2 = p[i0 + 2 * CTHR];
      float4 v3 = p[i0 + 3 * CTHR];
      float4 v4 = p[i0 + 4 * CTHR];
      float4 v5 = p[i0 + 5 * CTHR];
      float4 v6 = p[i0 + 6 * CTHR];
      float4 v7 = p[i0 + 7 * CTHR];
      PROC(v0, i0);
      PROC(v1, i0 + 1 * CTHR);
      PROC(v2, i0 + 2 * CTHR);
      PROC(v3, i0 + 3 * CTHR);
      PROC(v4, i0 + 4 * CTHR);
      PROC(v5, i0 + 5 * CTHR);
      PROC(v6, i0 + 6 * CTHR);
      PROC(v7, i0 + 7 * CTHR);
    } else {
      for (int k = 0; k < 8; ++k) {
        int idx = i0 + k * CTHR;
        if (idx < IMG_F4) { float4 v = p[idx]; PROC(v, idx); }
      }
    }
  }
#undef PROC
  __syncthreads();
  // flush: wave w handles classes w, w+4, ...; no global atomics
  int w = tid >> 6, lane = tid & 63;
  int gblk = b * CBLK + blk;
  for (int c = w; c < CLS; c += 4) {
    int cnt = lcnt[c];
    if (lane == 0) bcnt[gblk * CLS + c] = cnt;   // real count (may exceed BCAP -> fallback)
    int ns = cnt < BCAP ? cnt : BCAP;
    if (lane < ns) bdata[((size_t)(gblk * CLS + c)) * BCAP + lane] = ldata[c][lane];
  }
}

// ---- reduce per-block counts -> ccount per (b,c), overflow sentinel forces fallback ----
__global__ void k_sum(const int* __restrict__ bcnt, int* __restrict__ ccount) {
  int c = blockIdx.x, b = blockIdx.y;
  int lane = threadIdx.x;  // 64
  int s = 0, mx = 0;
  for (int j = lane; j < CBLK; j += 64) {
    int v = bcnt[(b * CBLK + j) * CLS + c];
    s += v; mx = v > mx ? v : mx;
  }
#pragma unroll
  for (int o = 32; o >= 1; o >>= 1) {
    s += __shfl_xor(s, o, 64);
    int m2 = __shfl_xor(mx, o, 64);
    mx = m2 > mx ? m2 : mx;
  }
  if (lane == 0) ccount[b * CLS + c] = (mx > BCAP || s > CAND_CAP) ? CAND_CAP + 1 : s;
}

// ---- fallback chain (exactness for arbitrary inputs; no-ops for this data) ----
__global__ __launch_bounds__(256) void k_fb_hist(const float* __restrict__ cls,
                                                 const int* __restrict__ ccount, int* __restrict__ hist) {
  int slab = blockIdx.x, b = blockIdx.y;
  bool need = false;
  for (int c = threadIdx.x; c < CLS; c += 256) {
    int cnt = ccount[b * CLS + c];
    if (cnt < K_PRE || cnt > CAND_CAP) need = true;
  }
  __shared__ int sneed;
  if (threadIdx.x == 0) sneed = 0;
  __syncthreads();
  if (__ballot(need)) if ((threadIdx.x & 63) == 0) atomicOr(&sneed, 1);
  __syncthreads();
  if (!sneed) return;

  __shared__ int lh[CLS * NBINS];  // 40KB
  for (int i = threadIdx.x; i < CLS * NBINS; i += 256) lh[i] = 0;
  __syncthreads();
  const float4* base = (const float4*)(cls + ((size_t)b * NN + (size_t)slab * NPER) * CLS);
  for (int t = threadIdx.x; t < FPB / 4; t += 256) {
    float4 v = base[t];
    int i0 = t * 4;
    float vv[4] = {v.x, v.y, v.z, v.w};
#pragma unroll
    for (int k = 0; k < 4; ++k) {
      float s = vv[k];
      if (s > SCORE_TH) {
        int c = (i0 + k) % CLS;
        atomicAdd(&lh[c * NBINS + score_bin(s)], 1);
      }
    }
  }
  __syncthreads();
  int* gh = hist + (size_t)b * CLS * NBINS;
  for (int i = threadIdx.x; i < CLS * NBINS; i += 256) {
    int v = lh[i];
    if (v) atomicAdd(&gh[i], v);
  }
}

__global__ void k_fb_thr(const int* __restrict__ hist, int* __restrict__ thr, int* __restrict__ ccount) {
  int t = blockIdx.x * blockDim.x + threadIdx.x;
  if (t >= BB * CLS) return;
  int cnt = ccount[t];
  if (cnt >= K_PRE && cnt <= CAND_CAP) { thr[t] = NBINS; return; }  // fast path OK
  const int* h = hist + (size_t)t * NBINS;
  int sum = 0, bin = 0;
  for (int i = NBINS - 1; i >= 0; --i) {
    sum += h[i];
    if (sum >= K_PRE) { bin = i; break; }
  }
  thr[t] = bin;
  ccount[t] = 0;
}

__global__ __launch_bounds__(256) void k_fb_collect(const float* __restrict__ cls, const int* __restrict__ thr,
                                                    int* __restrict__ ccount, u64* __restrict__ cand) {
  __shared__ int lthr[CLS];
  __shared__ int sneed;
  int slab = blockIdx.x, b = blockIdx.y;
  if (threadIdx.x == 0) sneed = 0;
  __syncthreads();
  if (threadIdx.x < CLS) {
    int tv = thr[b * CLS + threadIdx.x];
    lthr[threadIdx.x] = tv;
    if (tv < NBINS) atomicOr(&sneed, 1);
  }
  __syncthreads();
  if (!sneed) return;
  const float4* base = (const float4*)(cls + ((size_t)b * NN + (size_t)slab * NPER) * CLS);
  int n0 = slab * NPER;
  for (int t = threadIdx.x; t < FPB / 4; t += 256) {
    float4 v = base[t];
    int i0 = t * 4;
    float vv[4] = {v.x, v.y, v.z, v.w};
#pragma unroll
    for (int k = 0; k < 4; ++k) {
      float s = vv[k];
      if (s > SCORE_TH) {
        int idx = i0 + k;
        int c = idx % CLS;
        if (score_bin(s) >= lthr[c]) {
          int pos = atomicAdd(&ccount[b * CLS + c], 1);
          if (pos < CAND_CAP) {
            int anchor = n0 + idx / CLS;
            cand[((size_t)(b * CLS + c)) * CAND_CAP + pos] =
                ((u64)__float_as_uint(s) << 32) | (u64)(0xFFFFFFFFu - (unsigned)anchor);
          }
        }
      }
    }
  }
}

// ---- per-(b,c): gather candidates, exact top-500 sort, greedy NMS, compact ----
__global__ __launch_bounds__(1024) void k_nms(const float* __restrict__ boxes, const int* __restrict__ ccount,
                                              const int* __restrict__ thr, const int* __restrict__ bcnt,
                                              const u64* __restrict__ bdata, const u64* __restrict__ cand,
                                              u64* __restrict__ cselk, int* __restrict__ csela,
                                              int* __restrict__ ksel) {
  __shared__ u64 keys[CAND_CAP];  // 32KB; candidates, then reused as sup[500][8]
  __shared__ float sx1[K_PRE], sy1[K_PRE], sx2[K_PRE], sy2[K_PRE], sar[K_PRE], ssc[K_PRE];
  __shared__ int sanchor[K_PRE];
  __shared__ u64 keepw[8];
  __shared__ int scnt[CBLK], soff[CBLK + 1];
  int bc = blockIdx.x;
  int b = bc / CLS, c = bc % CLS;
  int tid = threadIdx.x;
  int m;

  if (thr[bc] == NBINS) {
    // fast path: gather from per-block regions (counts guaranteed <= BCAP, sum <= CAND_CAP)
    if (tid < CBLK) scnt[tid] = bcnt[(b * CBLK + tid) * CLS + c];
    __syncthreads();
    if (tid == 0) {
      int acc = 0;
      for (int j = 0; j < CBLK; ++j) { soff[j] = acc; acc += scnt[j]; }
      soff[CBLK] = acc;
    }
    __syncthreads();
    m = soff[CBLK];
    for (int e = tid; e < CBLK * BCAP; e += 1024) {
      int j = e >> 5, s = e & (BCAP - 1);
      if (s < scnt[j]) keys[soff[j] + s] = bdata[((size_t)((b * CBLK + j) * CLS + c)) * BCAP + s];
    }
  } else {
    m = ccount[bc]; if (m > CAND_CAP) m = CAND_CAP;
    for (int i = tid; i < m; i += 1024) keys[i] = cand[(size_t)bc * CAND_CAP + i];
  }
  int nsort = 1024; while (nsort < m) nsort <<= 1;
  for (int i = m + tid; i < nsort; i += 1024) keys[i] = 0ULL;
  __syncthreads();

  if (nsort <= 1024) {
    // in-register bitonic, descending; shfl_xor for j<64, LDS exchange for j>=64
    u64 key = keys[tid];
    __syncthreads();
    for (int k2 = 2; k2 <= 1024; k2 <<= 1) {
      for (int j = k2 >> 1; j > 0; j >>= 1) {
        u64 other;
        if (j >= 64) {
          keys[tid] = key; __syncthreads();
          other = keys[tid ^ j]; __syncthreads();
        } else {
          other = shflx64(key, j);
        }
        bool keepmax = (((tid & k2) == 0) == ((tid & j) == 0));
        key = keepmax ? (key >= other ? key : other) : (key <= other ? key : other);
      }
    }
    keys[tid] = key;
    __syncthreads();
  } else {
    // LDS bitonic up to 4096 (rare)
    for (int k2 = 2; k2 <= nsort; k2 <<= 1) {
      for (int j = k2 >> 1; j > 0; j >>= 1) {
        for (int i = tid; i < nsort; i += 1024) {
          int ij = i ^ j;
          if (ij > i) {
            u64 a = keys[i], bv = keys[ij];
            bool up = ((i & k2) == 0);
            if (up ? (a < bv) : (a > bv)) { keys[i] = bv; keys[ij] = a; }
          }
        }
        __syncthreads();
      }
    }
  }

  // extract top-500 fragments
  bool val = false;
  if (tid < K_PRE) {
    u64 key = keys[tid];
    float sc = __uint_as_float((unsigned)(key >> 32));
    unsigned anchor = 0xFFFFFFFFu - (unsigned)(key & 0xFFFFFFFFu);
    val = sc > SCORE_TH;
    if (!val || anchor >= NN) anchor = 0;
    float4 bx = *(const float4*)(boxes + ((size_t)b * NN + anchor) * 4);
    sx1[tid] = bx.x; sy1[tid] = bx.y; sx2[tid] = bx.z; sy2[tid] = bx.w;
    sar[tid] = fmaxf(bx.z - bx.x, 0.0f) * fmaxf(bx.w - bx.y, 0.0f);
    ssc[tid] = sc; sanchor[tid] = (int)anchor;
  }
  u64 bm = __ballot(val);
  if ((tid & 63) == 0 && tid < 512) keepw[tid >> 6] = bm;
  __syncthreads();
  // zero + build suppression bitmatrix (iou>0.5 & j>i), exact reference fp32 arithmetic
  for (int i = tid; i < K_PRE * 8; i += 1024) keys[i] = 0ULL;
  __syncthreads();
  for (int tt = tid; tt < K_PRE * 8; tt += 1024) {
    int i = tt >> 3, w = tt & 7;
    float xi1 = sx1[i], yi1 = sy1[i], xi2 = sx2[i], yi2 = sy2[i], ai = sar[i];
    int j0 = w << 6;
    int jend = (j0 + 64 < K_PRE) ? j0 + 64 : K_PRE;
    int jst = (j0 > i + 1) ? j0 : i + 1;
    u64 word = 0;
    for (int j = jst; j < jend; ++j) {
      float iw = fmaxf(fminf(xi2, sx2[j]) - fmaxf(xi1, sx1[j]), 0.0f);
      float ih = fmaxf(fminf(yi2, sy2[j]) - fmaxf(yi1, sy1[j]), 0.0f);
      float inter = iw * ih;
      float denom = fmaxf(ai + sar[j] - inter, 1e-8f);
      if (inter / denom > NMS_THR) word |= 1ULL << (j - j0);
    }
    keys[i * 8 + w] = word;
  }
  __syncthreads();
  // greedy sweep: lanes 0-7 of wave 0 own the 8 keep words; row i+1 prefetched
  if (tid < 64) {
    u64 kw = (tid < 8) ? keepw[tid] : 0ULL;
    u64 row = (tid < 8) ? keys[tid] : 0ULL;  // row 0
    for (int i = 0; i < K_PRE; ++i) {
      u64 nrow = (tid < 8 && i + 1 < K_PRE) ? keys[(i + 1) * 8 + tid] : 0ULL;
      int owner = i >> 6;
      unsigned bit = (unsigned)((kw >> (i & 63)) & 1ULL);
      bit = (unsigned)__shfl((int)bit, owner, 64);
      u64 msk = 0ULL - (u64)bit;
      kw &= ~(row & msk);
      row = nrow;
    }
    if (tid < 8) keepw[tid] = kw;
    int cnt = (tid < 8) ? __popcll(kw) : 0;
    cnt += __shfl_xor(cnt, 1, 64);
    cnt += __shfl_xor(cnt, 2, 64);
    cnt += __shfl_xor(cnt, 4, 64);
    if (tid == 0) ksel[bc] = cnt > MAXDET ? MAXDET : cnt;
  }
  __syncthreads();
  // rank (cumsum-1) and compact survivors with rank < 300
  if (tid < K_PRE) {
    int w = tid >> 6, bpos = tid & 63;
    u64 kw = keepw[w];
    if ((kw >> bpos) & 1ULL) {
      int rank = 0;
      for (int ww = 0; ww < w; ++ww) rank += __popcll(keepw[ww]);
      rank += __popcll(kw & ((1ULL << bpos) - 1ULL));
      if (rank < MAXDET) {
        unsigned flat = (unsigned)(c * K_PRE + tid);  // tie-break: lower flat index first
        cselk[(size_t)bc * MAXDET + rank] = ((u64)__float_as_uint(ssc[tid]) << 32) | (u64)(0xFFFFFFFFu - flat);
        csela[(size_t)bc * MAXDET + rank] = sanchor[tid];
      }
    }
  }
}

// ---- per-image: 20-way tournament merge of sorted survivor lists -> global top-300 ----
__global__ __launch_bounds__(256) void k_out(const float* __restrict__ boxes, const u64* __restrict__ cselk,
                                             const int* __restrict__ csela, const int* __restrict__ ksel,
                                             float* __restrict__ out) {
  __shared__ u64 skey[CLS][MAXDET];  // 48KB
  __shared__ int skc[CLS];
  __shared__ int winc[MAXDET];
  __shared__ float winsc[MAXDET];
  int b = blockIdx.x, tid = threadIdx.x;
  if (tid < CLS) skc[tid] = ksel[b * CLS + tid];
  __syncthreads();
  for (int t = tid; t < CLS * MAXDET; t += 256) {
    int c = t / MAXDET, p = t % MAXDET;
    skey[c][p] = (p < skc[c]) ? cselk[(size_t)(b * CLS + c) * MAXDET + p] : 0ULL;
  }
  __syncthreads();
  if (tid < 64) {
    int lane = tid;
    u64 cur = 0, nxt = 0; int p = 0, kc = 0;
    if (lane < CLS) {
      kc = skc[lane];
      cur = kc > 0 ? skey[lane][0] : 0ULL;
      nxt = kc > 1 ? skey[lane][1] : 0ULL;
    }
    for (int i = 0; i < MAXDET; ++i) {
      u64 mx = cur;
#pragma unroll
      for (int off = 16; off >= 1; off >>= 1) {  // heads live in lanes 0..19
        unsigned hi = __shfl_xor((int)(unsigned)(mx >> 32), off, 32);
        unsigned lo = __shfl_xor((int)(unsigned)(mx & 0xFFFFFFFFu), off, 32);
        u64 o = ((u64)hi << 32) | lo;
        if (o > mx) mx = o;
      }
      if (mx != 0ULL && cur == mx) {  // keys unique -> exactly one winner
        winc[i] = (lane << 16) | p;
        winsc[i] = __uint_as_float((unsigned)(mx >> 32));
        ++p;
        cur = nxt;
        nxt = (p + 1 < kc) ? skey[lane][p + 1] : 0ULL;
      }
      if (mx == 0ULL && lane == 0) winc[i] = -1;
    }
  }
  __syncthreads();
  for (int i = tid; i < MAXDET; i += 256) {
    int wc = winc[i];
    float4 bx; float sc, lb;
    if (wc < 0) {
      bx = make_float4(-1.f, -1.f, -1.f, -1.f); sc = -1.f; lb = -1.f;
    } else {
      int c = wc >> 16, p = wc & 0xFFFF;
      int anchor = csela[(size_t)(b * CLS + c) * MAXDET + p];
      bx = *(const float4*)(boxes + ((size_t)b * NN + anchor) * 4);
      sc = winsc[i];
      lb = (float)(c - 1);  // reference: out_labels = fl - 1
    }
    *(float4*)(out + ((size_t)b * MAXDET + i) * 4) = bx;
    out[BB * MAXDET * 4 + b * MAXDET + i] = sc;
    out[BB * MAXDET * 4 + BB * MAXDET + b * MAXDET + i] = lb;
  }
}

extern "C" void kernel_launch(void* const* d_in, const int* in_sizes, int n_in,
                              void* d_out, int out_size, void* d_ws, size_t ws_size,
                              hipStream_t stream) {
  (void)in_sizes; (void)n_in; (void)out_size; (void)ws_size;
  const float* boxes = (const float*)d_in[0];
  const float* cls = (const float*)d_in[1];
  float* out = (float*)d_out;
  char* ws = (char*)d_ws;
  int* hist   = (int*)(ws + HIST_OFF);
  int* thr    = (int*)(ws + THR_OFF);
  int* ccount = (int*)(ws + CCNT_OFF);
  int* ksel   = (int*)(ws + KSEL_OFF);
  u64* cand   = (u64*)(ws + CAND_OFF);
  u64* cselk  = (u64*)(ws + CSELK_OFF);
  int* csela  = (int*)(ws + CSELA_OFF);
  int* bcnt   = (int*)(ws + BCNT_OFF);
  u64* bdata  = (u64*)(ws + BDATA_OFF);

  hipMemsetAsync(ws, 0, ZERO_BYTES, stream);
  k_collect<<<dim3(CBLK, BB), CTHR, 0, stream>>>(cls, bcnt, bdata);
  k_sum<<<dim3(CLS, BB), 64, 0, stream>>>(bcnt, ccount);
  k_fb_hist<<<dim3(SLABS, BB), 256, 0, stream>>>(cls, ccount, hist);
  k_fb_thr<<<1, 256, 0, stream>>>(hist, thr, ccount);
  k_fb_collect<<<dim3(SLABS, BB), 256, 0, stream>>>(cls, thr, ccount, cand);
  k_nms<<<BB * CLS, 1024, 0, stream>>>(boxes, ccount, thr, bcnt, bdata, cand, cselk, csela, ksel);
  k_out<<<BB, 256, 0, stream>>>(boxes, cselk, csela, ksel, out);
}

// Round 5
// 247.307 us; speedup vs baseline: 2.9762x; 1.1009x over previous
//
#include <hip/hip_runtime.h>
#include <stdint.h>

typedef unsigned long long u64;

#define BB 8
#define NN 200000
#define CLS 20
#define K_PRE 500
#define MAXDET 300
#define SCORE_TH 0.05f
#define NMS_THR 0.5f

#define NBINS 512
#define CAND_CAP 4096

// fast path: fixed conservative collect threshold (uniform scores -> ~842/class >> 500)
// exactness for arbitrary inputs preserved by the histogram fallback chain.
#define T_COL 0.996f

// collect geometry: 128 blocks/image, 256 thr, 8 named loads in flight, contiguous 32KB chunks
#define CBLK 128
#define CTHR 256
#define IMG_F4 1000000            // NN*CLS/4 float4 per image
#define ITERS 4                   // 4 * 8*256 = 8192 float4 per block
#define BCAP 32                   // per block-class staging capacity (lambda ~6.6)

// fallback grid (old histogram path; no-op in practice)
#define SLABS 25
#define NPER (NN / SLABS)
#define FPB (NPER * CLS)

static constexpr float BINSCALE = (float)NBINS / 0.95f;

// ws layout (bytes)
#define HIST_OFF 0              // 8*20*512*4 = 327680
#define THR_OFF  327680         // 640
#define CCNT_OFF 328320         // 640
#define KSEL_OFF 328960         // 640
#define ZERO_BYTES 329600
#define CAND_OFF 329600         // 160*4096*8 = 5242880
#define CSELK_OFF 5572480       // 160*300*8 = 384000
#define CSELA_OFF 5956480       // 160*300*4 = 192000
#define BCNT_OFF 6148480        // 1024*20*4 = 81920
#define BDATA_OFF 6230400       // 1024*20*32*8 = 5242880  (end 11473280)

__device__ __forceinline__ int score_bin(float s) {
  int b = (int)((s - SCORE_TH) * BINSCALE);
  return b < 0 ? 0 : (b > NBINS - 1 ? NBINS - 1 : b);
}

__device__ __forceinline__ u64 shflx64(u64 v, int mask) {
  int hi = __shfl_xor((int)(unsigned)(v >> 32), mask, 64);
  int lo = __shfl_xor((int)(unsigned)(v & 0xFFFFFFFFu), mask, 64);
  return ((u64)(unsigned)hi << 32) | (unsigned)lo;
}

// ---- streaming pass: zero global atomics, LDS staging, per-block output region ----
__global__ __launch_bounds__(256) void k_collect(const float* __restrict__ cls,
                                                 int* __restrict__ bcnt, u64* __restrict__ bdata) {
  __shared__ u64 ldata[CLS][BCAP];   // 5KB
  __shared__ int lcnt[CLS];
  int tid = threadIdx.x;
  if (tid < CLS) lcnt[tid] = 0;
  __syncthreads();
  int blk = blockIdx.x, b = blockIdx.y;
  const float4* p = (const float4*)(cls + (size_t)b * IMG_F4 * 4);
  int base0 = blk * (ITERS * 8 * CTHR);
  bool full = (base0 + ITERS * 8 * CTHR) <= IMG_F4;

#define PROC(v, fidx) { \
    float m4_ = fmaxf(fmaxf((v).x, (v).y), fmaxf((v).z, (v).w)); \
    if (m4_ > T_COL) { \
      float vv_[4] = {(v).x, (v).y, (v).z, (v).w}; \
      _Pragma("unroll") \
      for (int e_ = 0; e_ < 4; ++e_) { \
        if (vv_[e_] > T_COL) { \
          int g_ = (fidx) * 4 + e_; \
          int c_ = g_ % CLS, a_ = g_ / CLS; \
          int li_ = atomicAdd(&lcnt[c_], 1); \
          if (li_ < BCAP) \
            ldata[c_][li_] = ((u64)__float_as_uint(vv_[e_]) << 32) | (u64)(0xFFFFFFFFu - (unsigned)a_); \
        } \
      } \
    } }

  for (int it = 0; it < ITERS; ++it) {
    int i0 = base0 + it * (8 * CTHR) + tid;
    if (full) {
      float4 v0 = p[i0];
      float4 v1 = p[i0 + 1 * CTHR];
      float4 v2 = p[i0 + 2 * CTHR];
      float4 v3 = p[i0 + 3 * CTHR];
      float4 v4 = p[i0 + 4 * CTHR];
      float4 v5 = p[i0 + 5 * CTHR];
      float4 v6 = p[i0 + 6 * CTHR];
      float4 v7 = p[i0 + 7 * CTHR];
      PROC(v0, i0);
      PROC(v1, i0 + 1 * CTHR);
      PROC(v2, i0 + 2 * CTHR);
      PROC(v3, i0 + 3 * CTHR);
      PROC(v4, i0 + 4 * CTHR);
      PROC(v5, i0 + 5 * CTHR);
      PROC(v6, i0 + 6 * CTHR);
      PROC(v7, i0 + 7 * CTHR);
    } else {
      for (int k = 0; k < 8; ++k) {
        int idx = i0 + k * CTHR;
        if (idx < IMG_F4) { float4 v = p[idx]; PROC(v, idx); }
      }
    }
  }
#undef PROC
  __syncthreads();
  // flush: wave w handles classes w, w+4, ...; no global atomics
  int w = tid >> 6, lane = tid & 63;
  int gblk = b * CBLK + blk;
  for (int c = w; c < CLS; c += 4) {
    int cnt = lcnt[c];
    if (lane == 0) bcnt[gblk * CLS + c] = cnt;   // real count (may exceed BCAP -> fallback)
    int ns = cnt < BCAP ? cnt : BCAP;
    if (lane < ns) bdata[((size_t)(gblk * CLS + c)) * BCAP + lane] = ldata[c][lane];
  }
}

// ---- reduce per-block counts -> ccount per (b,c), overflow sentinel forces fallback ----
__global__ void k_sum(const int* __restrict__ bcnt, int* __restrict__ ccount) {
  int c = blockIdx.x, b = blockIdx.y;
  int lane = threadIdx.x;  // 64
  int s = 0, mx = 0;
  for (int j = lane; j < CBLK; j += 64) {
    int v = bcnt[(b * CBLK + j) * CLS + c];
    s += v; mx = v > mx ? v : mx;
  }
#pragma unroll
  for (int o = 32; o >= 1; o >>= 1) {
    s += __shfl_xor(s, o, 64);
    int m2 = __shfl_xor(mx, o, 64);
    mx = m2 > mx ? m2 : mx;
  }
  if (lane == 0) ccount[b * CLS + c] = (mx > BCAP || s > CAND_CAP) ? CAND_CAP + 1 : s;
}

// ---- fallback chain (exactness for arbitrary inputs; no-ops for this data) ----
__global__ __launch_bounds__(256) void k_fb_hist(const float* __restrict__ cls,
                                                 const int* __restrict__ ccount, int* __restrict__ hist) {
  int slab = blockIdx.x, b = blockIdx.y;
  bool need = false;
  for (int c = threadIdx.x; c < CLS; c += 256) {
    int cnt = ccount[b * CLS + c];
    if (cnt < K_PRE || cnt > CAND_CAP) need = true;
  }
  __shared__ int sneed;
  if (threadIdx.x == 0) sneed = 0;
  __syncthreads();
  if (__ballot(need)) if ((threadIdx.x & 63) == 0) atomicOr(&sneed, 1);
  __syncthreads();
  if (!sneed) return;

  __shared__ int lh[CLS * NBINS];  // 40KB
  for (int i = threadIdx.x; i < CLS * NBINS; i += 256) lh[i] = 0;
  __syncthreads();
  const float4* base = (const float4*)(cls + ((size_t)b * NN + (size_t)slab * NPER) * CLS);
  for (int t = threadIdx.x; t < FPB / 4; t += 256) {
    float4 v = base[t];
    int i0 = t * 4;
    float vv[4] = {v.x, v.y, v.z, v.w};
#pragma unroll
    for (int k = 0; k < 4; ++k) {
      float s = vv[k];
      if (s > SCORE_TH) {
        int c = (i0 + k) % CLS;
        atomicAdd(&lh[c * NBINS + score_bin(s)], 1);
      }
    }
  }
  __syncthreads();
  int* gh = hist + (size_t)b * CLS * NBINS;
  for (int i = threadIdx.x; i < CLS * NBINS; i += 256) {
    int v = lh[i];
    if (v) atomicAdd(&gh[i], v);
  }
}

__global__ void k_fb_thr(const int* __restrict__ hist, int* __restrict__ thr, int* __restrict__ ccount) {
  int t = blockIdx.x * blockDim.x + threadIdx.x;
  if (t >= BB * CLS) return;
  int cnt = ccount[t];
  if (cnt >= K_PRE && cnt <= CAND_CAP) { thr[t] = NBINS; return; }  // fast path OK
  const int* h = hist + (size_t)t * NBINS;
  int sum = 0, bin = 0;
  for (int i = NBINS - 1; i >= 0; --i) {
    sum += h[i];
    if (sum >= K_PRE) { bin = i; break; }
  }
  thr[t] = bin;
  ccount[t] = 0;
}

__global__ __launch_bounds__(256) void k_fb_collect(const float* __restrict__ cls, const int* __restrict__ thr,
                                                    int* __restrict__ ccount, u64* __restrict__ cand) {
  __shared__ int lthr[CLS];
  __shared__ int sneed;
  int slab = blockIdx.x, b = blockIdx.y;
  if (threadIdx.x == 0) sneed = 0;
  __syncthreads();
  if (threadIdx.x < CLS) {
    int tv = thr[b * CLS + threadIdx.x];
    lthr[threadIdx.x] = tv;
    if (tv < NBINS) atomicOr(&sneed, 1);
  }
  __syncthreads();
  if (!sneed) return;
  const float4* base = (const float4*)(cls + ((size_t)b * NN + (size_t)slab * NPER) * CLS);
  int n0 = slab * NPER;
  for (int t = threadIdx.x; t < FPB / 4; t += 256) {
    float4 v = base[t];
    int i0 = t * 4;
    float vv[4] = {v.x, v.y, v.z, v.w};
#pragma unroll
    for (int k = 0; k < 4; ++k) {
      float s = vv[k];
      if (s > SCORE_TH) {
        int idx = i0 + k;
        int c = idx % CLS;
        if (score_bin(s) >= lthr[c]) {
          int pos = atomicAdd(&ccount[b * CLS + c], 1);
          if (pos < CAND_CAP) {
            int anchor = n0 + idx / CLS;
            cand[((size_t)(b * CLS + c)) * CAND_CAP + pos] =
                ((u64)__float_as_uint(s) << 32) | (u64)(0xFFFFFFFFu - (unsigned)anchor);
          }
        }
      }
    }
  }
}

// ---- per-(b,c): gather candidates, exact top-500 sort, greedy NMS, compact ----
__global__ __launch_bounds__(1024) void k_nms(const float* __restrict__ boxes, const int* __restrict__ ccount,
                                              const int* __restrict__ thr, const int* __restrict__ bcnt,
                                              const u64* __restrict__ bdata, const u64* __restrict__ cand,
                                              u64* __restrict__ cselk, int* __restrict__ csela,
                                              int* __restrict__ ksel) {
  __shared__ u64 keys[CAND_CAP];       // 32KB; candidates/sort, then reused as sup[500][8]
  __shared__ float4 sbox[K_PRE];       // 8KB  (x1,y1,x2,y2)
  __shared__ float sar[K_PRE], ssc[K_PRE];
  __shared__ int sanchor[K_PRE];
  __shared__ u64 keepw[8];
  __shared__ int scnt[CBLK], soff[CBLK + 1];
  int bc = blockIdx.x;
  int b = bc / CLS, c = bc % CLS;
  int tid = threadIdx.x;
  int m;

  if (thr[bc] == NBINS) {
    // fast path: gather from per-block regions (counts <= BCAP, sum <= CAND_CAP)
    if (tid < CBLK) scnt[tid] = bcnt[(b * CBLK + tid) * CLS + c];
    __syncthreads();
    // single-wave exclusive scan of 128 counts (2 per lane)
    if (tid < 64) {
      int a = scnt[2 * tid], bv = scnt[2 * tid + 1];
      int s = a + bv;
#pragma unroll
      for (int o = 1; o < 64; o <<= 1) {
        int t2 = __shfl_up(s, o, 64);
        if ((int)tid >= o) s += t2;
      }
      int excl = s - (a + bv);
      soff[2 * tid] = excl;
      soff[2 * tid + 1] = excl + a;
      if (tid == 63) soff[CBLK] = s;
    }
    __syncthreads();
    m = soff[CBLK];
    for (int e = tid; e < CBLK * BCAP; e += 1024) {
      int j = e >> 5, s = e & (BCAP - 1);
      if (s < scnt[j]) keys[soff[j] + s] = bdata[((size_t)((b * CBLK + j) * CLS + c)) * BCAP + s];
    }
  } else {
    m = ccount[bc]; if (m > CAND_CAP) m = CAND_CAP;
    for (int i = tid; i < m; i += 1024) keys[i] = cand[(size_t)bc * CAND_CAP + i];
  }
  int nsort = 1024; while (nsort < m) nsort <<= 1;
  for (int i = m + tid; i < nsort; i += 1024) keys[i] = 0ULL;
  __syncthreads();

  if (nsort <= 1024) {
    // in-register bitonic, descending; shfl_xor for j<64, LDS exchange for j>=64
    u64 key = keys[tid];
    __syncthreads();
    for (int k2 = 2; k2 <= 1024; k2 <<= 1) {
      for (int j = k2 >> 1; j > 0; j >>= 1) {
        u64 other;
        if (j >= 64) {
          keys[tid] = key; __syncthreads();
          other = keys[tid ^ j]; __syncthreads();
        } else {
          other = shflx64(key, j);
        }
        bool keepmax = (((tid & k2) == 0) == ((tid & j) == 0));
        key = keepmax ? (key >= other ? key : other) : (key <= other ? key : other);
      }
    }
    keys[tid] = key;
    __syncthreads();
  } else {
    // LDS bitonic up to 4096 (rare)
    for (int k2 = 2; k2 <= nsort; k2 <<= 1) {
      for (int j = k2 >> 1; j > 0; j >>= 1) {
        for (int i = tid; i < nsort; i += 1024) {
          int ij = i ^ j;
          if (ij > i) {
            u64 a = keys[i], bv = keys[ij];
            bool up = ((i & k2) == 0);
            if (up ? (a < bv) : (a > bv)) { keys[i] = bv; keys[ij] = a; }
          }
        }
        __syncthreads();
      }
    }
  }

  // extract top-500 fragments
  bool val = false;
  if (tid < K_PRE) {
    u64 key = keys[tid];
    float sc = __uint_as_float((unsigned)(key >> 32));
    unsigned anchor = 0xFFFFFFFFu - (unsigned)(key & 0xFFFFFFFFu);
    val = sc > SCORE_TH;
    if (!val || anchor >= NN) anchor = 0;
    float4 bx = *(const float4*)(boxes + ((size_t)b * NN + anchor) * 4);
    sbox[tid] = bx;
    sar[tid] = fmaxf(bx.z - bx.x, 0.0f) * fmaxf(bx.w - bx.y, 0.0f);
    ssc[tid] = sc; sanchor[tid] = (int)anchor;
  }
  u64 bm = __ballot(val);
  if ((tid & 63) == 0 && tid < 512) keepw[tid >> 6] = bm;
  __syncthreads();

  // suppression bitmatrix, transposed: thread owns column j (regs), rows via
  // wave-uniform broadcast reads; __ballot assembles each u64 word. No LDS
  // conflicts, no zero-init (every word of sup[500][8] written exactly once).
  {
    int half = tid >> 9;          // 0: rows 0..249, 1: rows 250..499
    int j = tid & 511;
    int jc = j < K_PRE ? j : 0;
    float4 bj = sbox[jc];
    float aj = sar[jc];
    bool jval = j < K_PRE;
    int w = (tid >> 6) & 7;       // word index within row == j>>6
    int i0r = half * (K_PRE / 2), i1r = i0r + (K_PRE / 2);
    for (int i = i0r; i < i1r; ++i) {
      float4 bi = sbox[i];        // broadcast (wave-uniform address)
      float ai = sar[i];          // broadcast
      float iw = fmaxf(fminf(bi.z, bj.z) - fmaxf(bi.x, bj.x), 0.0f);
      float ih = fmaxf(fminf(bi.w, bj.w) - fmaxf(bi.y, bj.y), 0.0f);
      float inter = iw * ih;
      float denom = fmaxf(ai + aj - inter, 1e-8f);
      bool pred = jval && (j > i) && (inter / denom > NMS_THR);
      u64 msk = __ballot(pred);
      if ((tid & 63) == 0) keys[i * 8 + w] = msk;
    }
  }
  __syncthreads();

  // greedy sweep: lanes 0-7 of wave 0 own the 8 keep words; row i+1 prefetched
  if (tid < 64) {
    u64 kw = (tid < 8) ? keepw[tid] : 0ULL;
    u64 row = (tid < 8) ? keys[tid] : 0ULL;  // row 0
    for (int i = 0; i < K_PRE; ++i) {
      u64 nrow = (tid < 8 && i + 1 < K_PRE) ? keys[(i + 1) * 8 + tid] : 0ULL;
      int owner = i >> 6;
      unsigned bit = (unsigned)((kw >> (i & 63)) & 1ULL);
      bit = (unsigned)__shfl((int)bit, owner, 64);
      u64 msk = 0ULL - (u64)bit;
      kw &= ~(row & msk);
      row = nrow;
    }
    if (tid < 8) keepw[tid] = kw;
    int cnt = (tid < 8) ? __popcll(kw) : 0;
    cnt += __shfl_xor(cnt, 1, 64);
    cnt += __shfl_xor(cnt, 2, 64);
    cnt += __shfl_xor(cnt, 4, 64);
    if (tid == 0) ksel[bc] = cnt > MAXDET ? MAXDET : cnt;
  }
  __syncthreads();
  // rank (cumsum-1) and compact survivors with rank < 300
  if (tid < K_PRE) {
    int w = tid >> 6, bpos = tid & 63;
    u64 kw = keepw[w];
    if ((kw >> bpos) & 1ULL) {
      int rank = 0;
      for (int ww = 0; ww < w; ++ww) rank += __popcll(keepw[ww]);
      rank += __popcll(kw & ((1ULL << bpos) - 1ULL));
      if (rank < MAXDET) {
        unsigned flat = (unsigned)(c * K_PRE + tid);  // tie-break: lower flat index first
        cselk[(size_t)bc * MAXDET + rank] = ((u64)__float_as_uint(ssc[tid]) << 32) | (u64)(0xFFFFFFFFu - flat);
        csela[(size_t)bc * MAXDET + rank] = sanchor[tid];
      }
    }
  }
}

// ---- per-image: 20-way tournament merge of sorted survivor lists -> global top-300 ----
__global__ __launch_bounds__(256) void k_out(const float* __restrict__ boxes, const u64* __restrict__ cselk,
                                             const int* __restrict__ csela, const int* __restrict__ ksel,
                                             float* __restrict__ out) {
  __shared__ u64 skey[CLS][MAXDET];  // 48KB
  __shared__ int skc[CLS];
  __shared__ int winc[MAXDET];
  __shared__ float winsc[MAXDET];
  int b = blockIdx.x, tid = threadIdx.x;
  if (tid < CLS) skc[tid] = ksel[b * CLS + tid];
  __syncthreads();
  for (int t = tid; t < CLS * MAXDET; t += 256) {
    int c = t / MAXDET, p = t % MAXDET;
    skey[c][p] = (p < skc[c]) ? cselk[(size_t)(b * CLS + c) * MAXDET + p] : 0ULL;
  }
  __syncthreads();
  if (tid < 64) {
    int lane = tid;
    u64 cur = 0, nxt = 0; int p = 0, kc = 0;
    if (lane < CLS) {
      kc = skc[lane];
      cur = kc > 0 ? skey[lane][0] : 0ULL;
      nxt = kc > 1 ? skey[lane][1] : 0ULL;
    }
    for (int i = 0; i < MAXDET; ++i) {
      u64 mx = cur;
#pragma unroll
      for (int off = 16; off >= 1; off >>= 1) {  // heads live in lanes 0..19
        unsigned hi = __shfl_xor((int)(unsigned)(mx >> 32), off, 32);
        unsigned lo = __shfl_xor((int)(unsigned)(mx & 0xFFFFFFFFu), off, 32);
        u64 o = ((u64)hi << 32) | lo;
        if (o > mx) mx = o;
      }
      if (mx != 0ULL && cur == mx) {  // keys unique -> exactly one winner
        winc[i] = (lane << 16) | p;
        winsc[i] = __uint_as_float((unsigned)(mx >> 32));
        ++p;
        cur = nxt;
        nxt = (p + 1 < kc) ? skey[lane][p + 1] : 0ULL;
      }
      if (mx == 0ULL && lane == 0) winc[i] = -1;
    }
  }
  __syncthreads();
  for (int i = tid; i < MAXDET; i += 256) {
    int wc = winc[i];
    float4 bx; float sc, lb;
    if (wc < 0) {
      bx = make_float4(-1.f, -1.f, -1.f, -1.f); sc = -1.f; lb = -1.f;
    } else {
      int c = wc >> 16, p = wc & 0xFFFF;
      int anchor = csela[(size_t)(b * CLS + c) * MAXDET + p];
      bx = *(const float4*)(boxes + ((size_t)b * NN + anchor) * 4);
      sc = winsc[i];
      lb = (float)(c - 1);  // reference: out_labels = fl - 1
    }
    *(float4*)(out + ((size_t)b * MAXDET + i) * 4) = bx;
    out[BB * MAXDET * 4 + b * MAXDET + i] = sc;
    out[BB * MAXDET * 4 + BB * MAXDET + b * MAXDET + i] = lb;
  }
}

extern "C" void kernel_launch(void* const* d_in, const int* in_sizes, int n_in,
                              void* d_out, int out_size, void* d_ws, size_t ws_size,
                              hipStream_t stream) {
  (void)in_sizes; (void)n_in; (void)out_size; (void)ws_size;
  const float* boxes = (const float*)d_in[0];
  const float* cls = (const float*)d_in[1];
  float* out = (float*)d_out;
  char* ws = (char*)d_ws;
  int* hist   = (int*)(ws + HIST_OFF);
  int* thr    = (int*)(ws + THR_OFF);
  int* ccount = (int*)(ws + CCNT_OFF);
  int* ksel   = (int*)(ws + KSEL_OFF);
  u64* cand   = (u64*)(ws + CAND_OFF);
  u64* cselk  = (u64*)(ws + CSELK_OFF);
  int* csela  = (int*)(ws + CSELA_OFF);
  int* bcnt   = (int*)(ws + BCNT_OFF);
  u64* bdata  = (u64*)(ws + BDATA_OFF);

  hipMemsetAsync(ws, 0, ZERO_BYTES, stream);
  k_collect<<<dim3(CBLK, BB), CTHR, 0, stream>>>(cls, bcnt, bdata);
  k_sum<<<dim3(CLS, BB), 64, 0, stream>>>(bcnt, ccount);
  k_fb_hist<<<dim3(SLABS, BB), 256, 0, stream>>>(cls, ccount, hist);
  k_fb_thr<<<1, 256, 0, stream>>>(hist, thr, ccount);
  k_fb_collect<<<dim3(SLABS, BB), 256, 0, stream>>>(cls, thr, ccount, cand);
  k_nms<<<BB * CLS, 1024, 0, stream>>>(boxes, ccount, thr, bcnt, bdata, cand, cselk, csela, ksel);
  k_out<<<BB, 256, 0, stream>>>(boxes, cselk, csela, ksel, out);
}

// Round 6
// 241.864 us; speedup vs baseline: 3.0432x; 1.0225x over previous
//
#include <hip/hip_runtime.h>
#include <stdint.h>

typedef unsigned long long u64;

#define BB 8
#define NN 200000
#define CLS 20
#define K_PRE 500
#define MAXDET 300
#define SCORE_TH 0.05f
#define NMS_THR 0.5f

#define NBINS 512
#define CAND_CAP 4096

// fast path: fixed conservative collect threshold (uniform scores -> ~842/class >> 500)
// exactness for arbitrary inputs preserved by the histogram fallback chain.
#define T_COL 0.996f

// collect geometry
#define CBLK 128
#define CTHR 256
#define IMG_F4 1000000
#define ITERS 4
#define BCAP 32

// fallback grid
#define SLABS 25
#define NPER (NN / SLABS)
#define FPB (NPER * CLS)

static constexpr float BINSCALE = (float)NBINS / 0.95f;

// ws layout (bytes)
#define HIST_OFF 0              // 327680
#define THR_OFF  327680
#define CCNT_OFF 328320
#define KSEL_OFF 328960
#define ZERO_BYTES 329600
#define CAND_OFF 329600         // 160*4096*8 = 5242880 ; REUSED as sup[bc][8][512] after k_sortgather
#define CSELK_OFF 5572480       // 160*300*8
#define CSELA_OFF 5956480       // 160*300*4
#define BCNT_OFF 6148480        // 1024*20*4
#define BDATA_OFF 6230400       // 1024*20*32*8 -> end 11473280
#define SKEY_OFF 11473280       // 160*512*8 = 655360
#define SBOX_OFF 12128640       // 160*500*16 = 1280000
#define SAR_OFF  13408640       // 160*500*4 = 320000
#define KEEPI_OFF 13728640      // 160*8*8 = 10240 -> end 13738880

__device__ __forceinline__ int score_bin(float s) {
  int b = (int)((s - SCORE_TH) * BINSCALE);
  return b < 0 ? 0 : (b > NBINS - 1 ? NBINS - 1 : b);
}

__device__ __forceinline__ u64 shflx64(u64 v, int mask) {
  int hi = __shfl_xor((int)(unsigned)(v >> 32), mask, 64);
  int lo = __shfl_xor((int)(unsigned)(v & 0xFFFFFFFFu), mask, 64);
  return ((u64)(unsigned)hi << 32) | (unsigned)lo;
}

// ---- streaming pass: zero global atomics, LDS staging, per-block output region ----
__global__ __launch_bounds__(256) void k_collect(const float* __restrict__ cls,
                                                 int* __restrict__ bcnt, u64* __restrict__ bdata) {
  __shared__ u64 ldata[CLS][BCAP];
  __shared__ int lcnt[CLS];
  int tid = threadIdx.x;
  if (tid < CLS) lcnt[tid] = 0;
  __syncthreads();
  int blk = blockIdx.x, b = blockIdx.y;
  const float4* p = (const float4*)(cls + (size_t)b * IMG_F4 * 4);
  int base0 = blk * (ITERS * 8 * CTHR);
  bool full = (base0 + ITERS * 8 * CTHR) <= IMG_F4;

#define PROC(v, fidx) { \
    float m4_ = fmaxf(fmaxf((v).x, (v).y), fmaxf((v).z, (v).w)); \
    if (m4_ > T_COL) { \
      float vv_[4] = {(v).x, (v).y, (v).z, (v).w}; \
      _Pragma("unroll") \
      for (int e_ = 0; e_ < 4; ++e_) { \
        if (vv_[e_] > T_COL) { \
          int g_ = (fidx) * 4 + e_; \
          int c_ = g_ % CLS, a_ = g_ / CLS; \
          int li_ = atomicAdd(&lcnt[c_], 1); \
          if (li_ < BCAP) \
            ldata[c_][li_] = ((u64)__float_as_uint(vv_[e_]) << 32) | (u64)(0xFFFFFFFFu - (unsigned)a_); \
        } \
      } \
    } }

  for (int it = 0; it < ITERS; ++it) {
    int i0 = base0 + it * (8 * CTHR) + tid;
    if (full) {
      float4 v0 = p[i0];
      float4 v1 = p[i0 + 1 * CTHR];
      float4 v2 = p[i0 + 2 * CTHR];
      float4 v3 = p[i0 + 3 * CTHR];
      float4 v4 = p[i0 + 4 * CTHR];
      float4 v5 = p[i0 + 5 * CTHR];
      float4 v6 = p[i0 + 6 * CTHR];
      float4 v7 = p[i0 + 7 * CTHR];
      PROC(v0, i0);
      PROC(v1, i0 + 1 * CTHR);
      PROC(v2, i0 + 2 * CTHR);
      PROC(v3, i0 + 3 * CTHR);
      PROC(v4, i0 + 4 * CTHR);
      PROC(v5, i0 + 5 * CTHR);
      PROC(v6, i0 + 6 * CTHR);
      PROC(v7, i0 + 7 * CTHR);
    } else {
      for (int k = 0; k < 8; ++k) {
        int idx = i0 + k * CTHR;
        if (idx < IMG_F4) { float4 v = p[idx]; PROC(v, idx); }
      }
    }
  }
#undef PROC
  __syncthreads();
  int w = tid >> 6, lane = tid & 63;
  int gblk = b * CBLK + blk;
  for (int c = w; c < CLS; c += 4) {
    int cnt = lcnt[c];
    if (lane == 0) bcnt[gblk * CLS + c] = cnt;
    int ns = cnt < BCAP ? cnt : BCAP;
    if (lane < ns) bdata[((size_t)(gblk * CLS + c)) * BCAP + lane] = ldata[c][lane];
  }
}

// ---- reduce per-block counts -> ccount per (b,c), overflow sentinel forces fallback ----
__global__ void k_sum(const int* __restrict__ bcnt, int* __restrict__ ccount) {
  int c = blockIdx.x, b = blockIdx.y;
  int lane = threadIdx.x;
  int s = 0, mx = 0;
  for (int j = lane; j < CBLK; j += 64) {
    int v = bcnt[(b * CBLK + j) * CLS + c];
    s += v; mx = v > mx ? v : mx;
  }
#pragma unroll
  for (int o = 32; o >= 1; o >>= 1) {
    s += __shfl_xor(s, o, 64);
    int m2 = __shfl_xor(mx, o, 64);
    mx = m2 > mx ? m2 : mx;
  }
  if (lane == 0) ccount[b * CLS + c] = (mx > BCAP || s > CAND_CAP) ? CAND_CAP + 1 : s;
}

// ---- fallback chain (exactness for arbitrary inputs; no-ops for this data) ----
__global__ __launch_bounds__(256) void k_fb_hist(const float* __restrict__ cls,
                                                 const int* __restrict__ ccount, int* __restrict__ hist) {
  int slab = blockIdx.x, b = blockIdx.y;
  bool need = false;
  for (int c = threadIdx.x; c < CLS; c += 256) {
    int cnt = ccount[b * CLS + c];
    if (cnt < K_PRE || cnt > CAND_CAP) need = true;
  }
  __shared__ int sneed;
  if (threadIdx.x == 0) sneed = 0;
  __syncthreads();
  if (__ballot(need)) if ((threadIdx.x & 63) == 0) atomicOr(&sneed, 1);
  __syncthreads();
  if (!sneed) return;

  __shared__ int lh[CLS * NBINS];
  for (int i = threadIdx.x; i < CLS * NBINS; i += 256) lh[i] = 0;
  __syncthreads();
  const float4* base = (const float4*)(cls + ((size_t)b * NN + (size_t)slab * NPER) * CLS);
  for (int t = threadIdx.x; t < FPB / 4; t += 256) {
    float4 v = base[t];
    int i0 = t * 4;
    float vv[4] = {v.x, v.y, v.z, v.w};
#pragma unroll
    for (int k = 0; k < 4; ++k) {
      float s = vv[k];
      if (s > SCORE_TH) {
        int c = (i0 + k) % CLS;
        atomicAdd(&lh[c * NBINS + score_bin(s)], 1);
      }
    }
  }
  __syncthreads();
  int* gh = hist + (size_t)b * CLS * NBINS;
  for (int i = threadIdx.x; i < CLS * NBINS; i += 256) {
    int v = lh[i];
    if (v) atomicAdd(&gh[i], v);
  }
}

__global__ void k_fb_thr(const int* __restrict__ hist, int* __restrict__ thr, int* __restrict__ ccount) {
  int t = blockIdx.x * blockDim.x + threadIdx.x;
  if (t >= BB * CLS) return;
  int cnt = ccount[t];
  if (cnt >= K_PRE && cnt <= CAND_CAP) { thr[t] = NBINS; return; }
  const int* h = hist + (size_t)t * NBINS;
  int sum = 0, bin = 0;
  for (int i = NBINS - 1; i >= 0; --i) {
    sum += h[i];
    if (sum >= K_PRE) { bin = i; break; }
  }
  thr[t] = bin;
  ccount[t] = 0;
}

__global__ __launch_bounds__(256) void k_fb_collect(const float* __restrict__ cls, const int* __restrict__ thr,
                                                    int* __restrict__ ccount, u64* __restrict__ cand) {
  __shared__ int lthr[CLS];
  __shared__ int sneed;
  int slab = blockIdx.x, b = blockIdx.y;
  if (threadIdx.x == 0) sneed = 0;
  __syncthreads();
  if (threadIdx.x < CLS) {
    int tv = thr[b * CLS + threadIdx.x];
    lthr[threadIdx.x] = tv;
    if (tv < NBINS) atomicOr(&sneed, 1);
  }
  __syncthreads();
  if (!sneed) return;
  const float4* base = (const float4*)(cls + ((size_t)b * NN + (size_t)slab * NPER) * CLS);
  int n0 = slab * NPER;
  for (int t = threadIdx.x; t < FPB / 4; t += 256) {
    float4 v = base[t];
    int i0 = t * 4;
    float vv[4] = {v.x, v.y, v.z, v.w};
#pragma unroll
    for (int k = 0; k < 4; ++k) {
      float s = vv[k];
      if (s > SCORE_TH) {
        int idx = i0 + k;
        int c = idx % CLS;
        if (score_bin(s) >= lthr[c]) {
          int pos = atomicAdd(&ccount[b * CLS + c], 1);
          if (pos < CAND_CAP) {
            int anchor = n0 + idx / CLS;
            cand[((size_t)(b * CLS + c)) * CAND_CAP + pos] =
                ((u64)__float_as_uint(s) << 32) | (u64)(0xFFFFFFFFu - (unsigned)anchor);
          }
        }
      }
    }
  }
}

// ---- per-(b,c): gather + exact top-500 bitonic sort + box fetch; writes sorted state to ws ----
__global__ __launch_bounds__(1024) void k_sortgather(const float* __restrict__ boxes,
                                                     const int* __restrict__ ccount, const int* __restrict__ thr,
                                                     const int* __restrict__ bcnt, const u64* __restrict__ bdata,
                                                     const u64* __restrict__ cand, u64* __restrict__ skey,
                                                     float4* __restrict__ sboxg, float* __restrict__ sarg,
                                                     u64* __restrict__ keepi) {
  __shared__ u64 keys[CAND_CAP];
  __shared__ int scnt[CBLK], soff[CBLK + 1];
  int bc = blockIdx.x;
  int b = bc / CLS;
  int tid = threadIdx.x;
  int m;

  if (thr[bc] == NBINS) {
    if (tid < CBLK) scnt[tid] = bcnt[(b * CBLK + tid) * CLS + (bc % CLS)];
    __syncthreads();
    if (tid < 64) {
      int a = scnt[2 * tid], bv = scnt[2 * tid + 1];
      int s = a + bv;
#pragma unroll
      for (int o = 1; o < 64; o <<= 1) {
        int t2 = __shfl_up(s, o, 64);
        if ((int)tid >= o) s += t2;
      }
      int excl = s - (a + bv);
      soff[2 * tid] = excl;
      soff[2 * tid + 1] = excl + a;
      if (tid == 63) soff[CBLK] = s;
    }
    __syncthreads();
    m = soff[CBLK];
    for (int e = tid; e < CBLK * BCAP; e += 1024) {
      int j = e >> 5, s = e & (BCAP - 1);
      if (s < scnt[j]) keys[soff[j] + s] = bdata[((size_t)((b * CBLK + j) * CLS + (bc % CLS))) * BCAP + s];
    }
  } else {
    m = ccount[bc]; if (m > CAND_CAP) m = CAND_CAP;
    for (int i = tid; i < m; i += 1024) keys[i] = cand[(size_t)bc * CAND_CAP + i];
  }
  int nsort = 1024; while (nsort < m) nsort <<= 1;
  for (int i = m + tid; i < nsort; i += 1024) keys[i] = 0ULL;
  __syncthreads();

  if (nsort <= 1024) {
    u64 key = keys[tid];
    __syncthreads();
    for (int k2 = 2; k2 <= 1024; k2 <<= 1) {
      for (int j = k2 >> 1; j > 0; j >>= 1) {
        u64 other;
        if (j >= 64) {
          keys[tid] = key; __syncthreads();
          other = keys[tid ^ j]; __syncthreads();
        } else {
          other = shflx64(key, j);
        }
        bool keepmax = (((tid & k2) == 0) == ((tid & j) == 0));
        key = keepmax ? (key >= other ? key : other) : (key <= other ? key : other);
      }
    }
    keys[tid] = key;
    __syncthreads();
  } else {
    for (int k2 = 2; k2 <= nsort; k2 <<= 1) {
      for (int j = k2 >> 1; j > 0; j >>= 1) {
        for (int i = tid; i < nsort; i += 1024) {
          int ij = i ^ j;
          if (ij > i) {
            u64 a = keys[i], bv = keys[ij];
            bool up = ((i & k2) == 0);
            if (up ? (a < bv) : (a > bv)) { keys[i] = bv; keys[ij] = a; }
          }
        }
        __syncthreads();
      }
    }
  }

  // write sorted keys, fetch boxes, init keep-words from validity
  if (tid < 512) {
    u64 key = (tid < K_PRE) ? keys[tid] : 0ULL;
    skey[(size_t)bc * 512 + tid] = key;
    float sc = __uint_as_float((unsigned)(key >> 32));
    unsigned anchor = 0xFFFFFFFFu - (unsigned)(key & 0xFFFFFFFFu);
    bool val = (tid < K_PRE) && (sc > SCORE_TH);
    if (!val || anchor >= NN) anchor = 0;
    float4 bx = *(const float4*)(boxes + ((size_t)b * NN + anchor) * 4);
    if (tid < K_PRE) {
      sboxg[(size_t)bc * K_PRE + tid] = bx;
      sarg[(size_t)bc * K_PRE + tid] = fmaxf(bx.z - bx.x, 0.0f) * fmaxf(bx.w - bx.y, 0.0f);
    }
    u64 bm = __ballot(val);
    if ((tid & 63) == 0) keepi[bc * 8 + (tid >> 6)] = bm;
  }
}

// ---- bitmatrix: grid (4, 160); block handles 128 rows x 512 cols; coalesced word stores ----
__global__ __launch_bounds__(1024) void k_bitmat(const float4* __restrict__ sboxg,
                                                 const float* __restrict__ sarg, u64* __restrict__ sup) {
  __shared__ float4 rbox[128];
  __shared__ float rar[128];
  int bc = blockIdx.y, rch = blockIdx.x;
  int tid = threadIdx.x;
  int half = tid >> 9;
  int j = tid & 511;
  int w = (tid >> 6) & 7;
  int lane = tid & 63;
  if (tid < 128) {
    int r = rch * 128 + tid;
    int rc = r < K_PRE ? r : 0;
    rbox[tid] = sboxg[(size_t)bc * K_PRE + rc];
    rar[tid] = sarg[(size_t)bc * K_PRE + rc];
  }
  __syncthreads();
  int jc = j < K_PRE ? j : 0;
  float4 bj = sboxg[(size_t)bc * K_PRE + jc];
  float aj = sarg[(size_t)bc * K_PRE + jc];
  bool jval = j < K_PRE;
  int i0 = rch * 128 + half * 64;
  u64 myword = 0;
  for (int k = 0; k < 64; ++k) {
    int i = i0 + k;
    float4 bi = rbox[half * 64 + k];
    float ai = rar[half * 64 + k];
    float iw = fmaxf(fminf(bi.z, bj.z) - fmaxf(bi.x, bj.x), 0.0f);
    float ih = fmaxf(fminf(bi.w, bj.w) - fmaxf(bi.y, bj.y), 0.0f);
    float inter = iw * ih;
    float denom = fmaxf(ai + aj - inter, 1e-8f);
    bool pred = jval && (j > i) && (inter / denom > NMS_THR);
    u64 msk = __ballot(pred);
    if (k == lane) myword = msk;
  }
  int i = i0 + lane;
  if (i < K_PRE) sup[(size_t)bc * 4096 + w * 512 + i] = myword;  // coalesced per wave
}

// ---- sweep: stage sup slice to LDS, serial greedy, rank+compact ----
#define SUPW 508
__global__ __launch_bounds__(512) void k_sweep(const u64* __restrict__ sup, const u64* __restrict__ keepi,
                                               const u64* __restrict__ skey, u64* __restrict__ cselk,
                                               int* __restrict__ csela, int* __restrict__ ksel) {
  __shared__ u64 lsup[8 * SUPW];  // ~32.5KB; banks (24w+2i)%32 -> 2-way (free)
  __shared__ u64 keepw[8];
  int bc = blockIdx.x;
  int c = bc % CLS;
  int tid = threadIdx.x;
  for (int idx = tid; idx < 4096; idx += 512) {
    int w = idx >> 9, i = idx & 511;
    if (i < K_PRE) lsup[w * SUPW + i] = sup[(size_t)bc * 4096 + idx];
  }
  if (tid < 8) keepw[tid] = keepi[bc * 8 + tid];
  __syncthreads();
  if (tid < 64) {
    u64 kw = (tid < 8) ? keepw[tid] : 0ULL;
    u64 row = (tid < 8) ? lsup[tid * SUPW] : 0ULL;
    for (int i = 0; i < K_PRE; ++i) {
      u64 nrow = (tid < 8 && i + 1 < K_PRE) ? lsup[tid * SUPW + i + 1] : 0ULL;
      int owner = i >> 6;
      unsigned bit = (unsigned)((kw >> (i & 63)) & 1ULL);
      bit = (unsigned)__shfl((int)bit, owner, 64);
      u64 msk = 0ULL - (u64)bit;
      kw &= ~(row & msk);
      row = nrow;
    }
    if (tid < 8) keepw[tid] = kw;
    int cnt = (tid < 8) ? __popcll(kw) : 0;
    cnt += __shfl_xor(cnt, 1, 64);
    cnt += __shfl_xor(cnt, 2, 64);
    cnt += __shfl_xor(cnt, 4, 64);
    if (tid == 0) ksel[bc] = cnt > MAXDET ? MAXDET : cnt;
  }
  __syncthreads();
  if (tid < K_PRE) {
    int w = tid >> 6, bpos = tid & 63;
    u64 kw = keepw[w];
    if ((kw >> bpos) & 1ULL) {
      int rank = 0;
      for (int ww = 0; ww < w; ++ww) rank += __popcll(keepw[ww]);
      rank += __popcll(kw & ((1ULL << bpos) - 1ULL));
      if (rank < MAXDET) {
        u64 key = skey[(size_t)bc * 512 + tid];
        float sc = __uint_as_float((unsigned)(key >> 32));
        unsigned anchor = 0xFFFFFFFFu - (unsigned)(key & 0xFFFFFFFFu);
        if (anchor >= NN) anchor = 0;
        unsigned flat = (unsigned)(c * K_PRE + tid);
        cselk[(size_t)bc * MAXDET + rank] = ((u64)__float_as_uint(sc) << 32) | (u64)(0xFFFFFFFFu - flat);
        csela[(size_t)bc * MAXDET + rank] = (int)anchor;
      }
    }
  }
}

// ---- per-image: 20-way tournament merge -> global top-300 ----
__global__ __launch_bounds__(256) void k_out(const float* __restrict__ boxes, const u64* __restrict__ cselk,
                                             const int* __restrict__ csela, const int* __restrict__ ksel,
                                             float* __restrict__ out) {
  __shared__ u64 skeym[CLS][MAXDET];
  __shared__ int skc[CLS];
  __shared__ int winc[MAXDET];
  __shared__ float winsc[MAXDET];
  int b = blockIdx.x, tid = threadIdx.x;
  if (tid < CLS) skc[tid] = ksel[b * CLS + tid];
  __syncthreads();
  for (int t = tid; t < CLS * MAXDET; t += 256) {
    int c = t / MAXDET, p = t % MAXDET;
    skeym[c][p] = (p < skc[c]) ? cselk[(size_t)(b * CLS + c) * MAXDET + p] : 0ULL;
  }
  __syncthreads();
  if (tid < 64) {
    int lane = tid;
    u64 cur = 0, nxt = 0; int p = 0, kc = 0;
    if (lane < CLS) {
      kc = skc[lane];
      cur = kc > 0 ? skeym[lane][0] : 0ULL;
      nxt = kc > 1 ? skeym[lane][1] : 0ULL;
    }
    for (int i = 0; i < MAXDET; ++i) {
      u64 mx = cur;
#pragma unroll
      for (int off = 16; off >= 1; off >>= 1) {
        unsigned hi = __shfl_xor((int)(unsigned)(mx >> 32), off, 32);
        unsigned lo = __shfl_xor((int)(unsigned)(mx & 0xFFFFFFFFu), off, 32);
        u64 o = ((u64)hi << 32) | lo;
        if (o > mx) mx = o;
      }
      if (mx != 0ULL && cur == mx) {
        winc[i] = (lane << 16) | p;
        winsc[i] = __uint_as_float((unsigned)(mx >> 32));
        ++p;
        cur = nxt;
        nxt = (p + 1 < kc) ? skeym[lane][p + 1] : 0ULL;
      }
      if (mx == 0ULL && lane == 0) winc[i] = -1;
    }
  }
  __syncthreads();
  for (int i = tid; i < MAXDET; i += 256) {
    int wc = winc[i];
    float4 bx; float sc, lb;
    if (wc < 0) {
      bx = make_float4(-1.f, -1.f, -1.f, -1.f); sc = -1.f; lb = -1.f;
    } else {
      int c = wc >> 16, p = wc & 0xFFFF;
      int anchor = csela[(size_t)(b * CLS + c) * MAXDET + p];
      bx = *(const float4*)(boxes + ((size_t)b * NN + anchor) * 4);
      sc = winsc[i];
      lb = (float)(c - 1);
    }
    *(float4*)(out + ((size_t)b * MAXDET + i) * 4) = bx;
    out[BB * MAXDET * 4 + b * MAXDET + i] = sc;
    out[BB * MAXDET * 4 + BB * MAXDET + b * MAXDET + i] = lb;
  }
}

extern "C" void kernel_launch(void* const* d_in, const int* in_sizes, int n_in,
                              void* d_out, int out_size, void* d_ws, size_t ws_size,
                              hipStream_t stream) {
  (void)in_sizes; (void)n_in; (void)out_size; (void)ws_size;
  const float* boxes = (const float*)d_in[0];
  const float* cls = (const float*)d_in[1];
  float* out = (float*)d_out;
  char* ws = (char*)d_ws;
  int* hist   = (int*)(ws + HIST_OFF);
  int* thr    = (int*)(ws + THR_OFF);
  int* ccount = (int*)(ws + CCNT_OFF);
  int* ksel   = (int*)(ws + KSEL_OFF);
  u64* cand   = (u64*)(ws + CAND_OFF);
  u64* cselk  = (u64*)(ws + CSELK_OFF);
  int* csela  = (int*)(ws + CSELA_OFF);
  int* bcnt   = (int*)(ws + BCNT_OFF);
  u64* bdata  = (u64*)(ws + BDATA_OFF);
  u64* skey   = (u64*)(ws + SKEY_OFF);
  float4* sboxg = (float4*)(ws + SBOX_OFF);
  float* sarg = (float*)(ws + SAR_OFF);
  u64* keepi  = (u64*)(ws + KEEPI_OFF);
  u64* sup    = cand;  // cand region reused as sup after k_sortgather

  hipMemsetAsync(ws, 0, ZERO_BYTES, stream);
  k_collect<<<dim3(CBLK, BB), CTHR, 0, stream>>>(cls, bcnt, bdata);
  k_sum<<<dim3(CLS, BB), 64, 0, stream>>>(bcnt, ccount);
  k_fb_hist<<<dim3(SLABS, BB), 256, 0, stream>>>(cls, ccount, hist);
  k_fb_thr<<<1, 256, 0, stream>>>(hist, thr, ccount);
  k_fb_collect<<<dim3(SLABS, BB), 256, 0, stream>>>(cls, thr, ccount, cand);
  k_sortgather<<<BB * CLS, 1024, 0, stream>>>(boxes, ccount, thr, bcnt, bdata, cand,
                                              skey, sboxg, sarg, keepi);
  k_bitmat<<<dim3(4, BB * CLS), 1024, 0, stream>>>(sboxg, sarg, sup);
  k_sweep<<<BB * CLS, 512, 0, stream>>>(sup, keepi, skey, cselk, csela, ksel);
  k_out<<<BB, 256, 0, stream>>>(boxes, cselk, csela, ksel, out);
}

// Round 7
// 158.710 us; speedup vs baseline: 4.6377x; 1.5239x over previous
//
#include <hip/hip_runtime.h>
#include <stdint.h>

typedef unsigned long long u64;

#define BB 8
#define NN 200000
#define CLS 20
#define K_PRE 500
#define MAXDET 300
#define SCORE_TH 0.05f
#define NMS_THR 0.5f

#define NBINS 512
#define CAND_CAP 4096

// fast path: fixed conservative collect threshold (uniform scores -> ~842/class >> 500)
// exactness for arbitrary inputs preserved by the histogram fallback chain.
#define T_COL 0.996f

// collect geometry
#define CBLK 128
#define CTHR 256
#define IMG_F4 1000000
#define ITERS 4
#define BCAP 32

// fallback grid
#define SLABS 25
#define NPER (NN / SLABS)
#define FPB (NPER * CLS)

static constexpr float BINSCALE = (float)NBINS / 0.95f;

// ws layout (bytes)
#define HIST_OFF 0              // 327680
#define THR_OFF  327680
#define CCNT_OFF 328320
#define KSEL_OFF 328960
#define ZERO_BYTES 329600
#define CAND_OFF 329600         // 160*4096*8 = 5242880 ; REUSED as sup[bc][8][512] after k_sortgather
#define CSELK_OFF 5572480       // 160*300*8
#define CSELA_OFF 5956480       // 160*300*4
#define BCNT_OFF 6148480        // 1024*20*4
#define BDATA_OFF 6230400       // 1024*20*32*8 -> end 11473280
#define SKEY_OFF 11473280       // 160*512*8 = 655360
#define SBOX_OFF 12128640       // 160*500*16 = 1280000
#define SAR_OFF  13408640       // 160*500*4 = 320000
#define KEEPI_OFF 13728640      // 160*8*8 = 10240 -> end 13738880

__device__ __forceinline__ int score_bin(float s) {
  int b = (int)((s - SCORE_TH) * BINSCALE);
  return b < 0 ? 0 : (b > NBINS - 1 ? NBINS - 1 : b);
}

__device__ __forceinline__ u64 shflx64(u64 v, int mask) {
  int hi = __shfl_xor((int)(unsigned)(v >> 32), mask, 64);
  int lo = __shfl_xor((int)(unsigned)(v & 0xFFFFFFFFu), mask, 64);
  return ((u64)(unsigned)hi << 32) | (unsigned)lo;
}

// ---- streaming pass: zero global atomics, LDS staging, per-block output region ----
__global__ __launch_bounds__(256) void k_collect(const float* __restrict__ cls,
                                                 int* __restrict__ bcnt, u64* __restrict__ bdata) {
  __shared__ u64 ldata[CLS][BCAP];
  __shared__ int lcnt[CLS];
  int tid = threadIdx.x;
  if (tid < CLS) lcnt[tid] = 0;
  __syncthreads();
  int blk = blockIdx.x, b = blockIdx.y;
  const float4* p = (const float4*)(cls + (size_t)b * IMG_F4 * 4);
  int base0 = blk * (ITERS * 8 * CTHR);
  bool full = (base0 + ITERS * 8 * CTHR) <= IMG_F4;

#define PROC(v, fidx) { \
    float m4_ = fmaxf(fmaxf((v).x, (v).y), fmaxf((v).z, (v).w)); \
    if (m4_ > T_COL) { \
      float vv_[4] = {(v).x, (v).y, (v).z, (v).w}; \
      _Pragma("unroll") \
      for (int e_ = 0; e_ < 4; ++e_) { \
        if (vv_[e_] > T_COL) { \
          int g_ = (fidx) * 4 + e_; \
          int c_ = g_ % CLS, a_ = g_ / CLS; \
          int li_ = atomicAdd(&lcnt[c_], 1); \
          if (li_ < BCAP) \
            ldata[c_][li_] = ((u64)__float_as_uint(vv_[e_]) << 32) | (u64)(0xFFFFFFFFu - (unsigned)a_); \
        } \
      } \
    } }

  for (int it = 0; it < ITERS; ++it) {
    int i0 = base0 + it * (8 * CTHR) + tid;
    if (full) {
      float4 v0 = p[i0];
      float4 v1 = p[i0 + 1 * CTHR];
      float4 v2 = p[i0 + 2 * CTHR];
      float4 v3 = p[i0 + 3 * CTHR];
      float4 v4 = p[i0 + 4 * CTHR];
      float4 v5 = p[i0 + 5 * CTHR];
      float4 v6 = p[i0 + 6 * CTHR];
      float4 v7 = p[i0 + 7 * CTHR];
      PROC(v0, i0);
      PROC(v1, i0 + 1 * CTHR);
      PROC(v2, i0 + 2 * CTHR);
      PROC(v3, i0 + 3 * CTHR);
      PROC(v4, i0 + 4 * CTHR);
      PROC(v5, i0 + 5 * CTHR);
      PROC(v6, i0 + 6 * CTHR);
      PROC(v7, i0 + 7 * CTHR);
    } else {
      for (int k = 0; k < 8; ++k) {
        int idx = i0 + k * CTHR;
        if (idx < IMG_F4) { float4 v = p[idx]; PROC(v, idx); }
      }
    }
  }
#undef PROC
  __syncthreads();
  int w = tid >> 6, lane = tid & 63;
  int gblk = b * CBLK + blk;
  for (int c = w; c < CLS; c += 4) {
    int cnt = lcnt[c];
    if (lane == 0) bcnt[gblk * CLS + c] = cnt;
    int ns = cnt < BCAP ? cnt : BCAP;
    if (lane < ns) bdata[((size_t)(gblk * CLS + c)) * BCAP + lane] = ldata[c][lane];
  }
}

// ---- reduce per-block counts -> ccount per (b,c), overflow sentinel forces fallback ----
__global__ void k_sum(const int* __restrict__ bcnt, int* __restrict__ ccount) {
  int c = blockIdx.x, b = blockIdx.y;
  int lane = threadIdx.x;
  int s = 0, mx = 0;
  for (int j = lane; j < CBLK; j += 64) {
    int v = bcnt[(b * CBLK + j) * CLS + c];
    s += v; mx = v > mx ? v : mx;
  }
#pragma unroll
  for (int o = 32; o >= 1; o >>= 1) {
    s += __shfl_xor(s, o, 64);
    int m2 = __shfl_xor(mx, o, 64);
    mx = m2 > mx ? m2 : mx;
  }
  if (lane == 0) ccount[b * CLS + c] = (mx > BCAP || s > CAND_CAP) ? CAND_CAP + 1 : s;
}

// ---- fallback chain (exactness for arbitrary inputs; no-ops for this data) ----
__global__ __launch_bounds__(256) void k_fb_hist(const float* __restrict__ cls,
                                                 const int* __restrict__ ccount, int* __restrict__ hist) {
  int slab = blockIdx.x, b = blockIdx.y;
  bool need = false;
  for (int c = threadIdx.x; c < CLS; c += 256) {
    int cnt = ccount[b * CLS + c];
    if (cnt < K_PRE || cnt > CAND_CAP) need = true;
  }
  __shared__ int sneed;
  if (threadIdx.x == 0) sneed = 0;
  __syncthreads();
  if (__ballot(need)) if ((threadIdx.x & 63) == 0) atomicOr(&sneed, 1);
  __syncthreads();
  if (!sneed) return;

  __shared__ int lh[CLS * NBINS];
  for (int i = threadIdx.x; i < CLS * NBINS; i += 256) lh[i] = 0;
  __syncthreads();
  const float4* base = (const float4*)(cls + ((size_t)b * NN + (size_t)slab * NPER) * CLS);
  for (int t = threadIdx.x; t < FPB / 4; t += 256) {
    float4 v = base[t];
    int i0 = t * 4;
    float vv[4] = {v.x, v.y, v.z, v.w};
#pragma unroll
    for (int k = 0; k < 4; ++k) {
      float s = vv[k];
      if (s > SCORE_TH) {
        int c = (i0 + k) % CLS;
        atomicAdd(&lh[c * NBINS + score_bin(s)], 1);
      }
    }
  }
  __syncthreads();
  int* gh = hist + (size_t)b * CLS * NBINS;
  for (int i = threadIdx.x; i < CLS * NBINS; i += 256) {
    int v = lh[i];
    if (v) atomicAdd(&gh[i], v);
  }
}

__global__ void k_fb_thr(const int* __restrict__ hist, int* __restrict__ thr, int* __restrict__ ccount) {
  int t = blockIdx.x * blockDim.x + threadIdx.x;
  if (t >= BB * CLS) return;
  int cnt = ccount[t];
  if (cnt >= K_PRE && cnt <= CAND_CAP) { thr[t] = NBINS; return; }
  const int* h = hist + (size_t)t * NBINS;
  int sum = 0, bin = 0;
  for (int i = NBINS - 1; i >= 0; --i) {
    sum += h[i];
    if (sum >= K_PRE) { bin = i; break; }
  }
  thr[t] = bin;
  ccount[t] = 0;
}

__global__ __launch_bounds__(256) void k_fb_collect(const float* __restrict__ cls, const int* __restrict__ thr,
                                                    int* __restrict__ ccount, u64* __restrict__ cand) {
  __shared__ int lthr[CLS];
  __shared__ int sneed;
  int slab = blockIdx.x, b = blockIdx.y;
  if (threadIdx.x == 0) sneed = 0;
  __syncthreads();
  if (threadIdx.x < CLS) {
    int tv = thr[b * CLS + threadIdx.x];
    lthr[threadIdx.x] = tv;
    if (tv < NBINS) atomicOr(&sneed, 1);
  }
  __syncthreads();
  if (!sneed) return;
  const float4* base = (const float4*)(cls + ((size_t)b * NN + (size_t)slab * NPER) * CLS);
  int n0 = slab * NPER;
  for (int t = threadIdx.x; t < FPB / 4; t += 256) {
    float4 v = base[t];
    int i0 = t * 4;
    float vv[4] = {v.x, v.y, v.z, v.w};
#pragma unroll
    for (int k = 0; k < 4; ++k) {
      float s = vv[k];
      if (s > SCORE_TH) {
        int idx = i0 + k;
        int c = idx % CLS;
        if (score_bin(s) >= lthr[c]) {
          int pos = atomicAdd(&ccount[b * CLS + c], 1);
          if (pos < CAND_CAP) {
            int anchor = n0 + idx / CLS;
            cand[((size_t)(b * CLS + c)) * CAND_CAP + pos] =
                ((u64)__float_as_uint(s) << 32) | (u64)(0xFFFFFFFFu - (unsigned)anchor);
          }
        }
      }
    }
  }
}

// ---- per-(b,c): gather + exact top-500 bitonic sort + box fetch; writes sorted state to ws ----
__global__ __launch_bounds__(1024) void k_sortgather(const float* __restrict__ boxes,
                                                     const int* __restrict__ ccount, const int* __restrict__ thr,
                                                     const int* __restrict__ bcnt, const u64* __restrict__ bdata,
                                                     const u64* __restrict__ cand, u64* __restrict__ skey,
                                                     float4* __restrict__ sboxg, float* __restrict__ sarg,
                                                     u64* __restrict__ keepi) {
  __shared__ u64 keys[CAND_CAP];
  __shared__ int scnt[CBLK], soff[CBLK + 1];
  int bc = blockIdx.x;
  int b = bc / CLS;
  int tid = threadIdx.x;
  int m;

  if (thr[bc] == NBINS) {
    if (tid < CBLK) scnt[tid] = bcnt[(b * CBLK + tid) * CLS + (bc % CLS)];
    __syncthreads();
    if (tid < 64) {
      int a = scnt[2 * tid], bv = scnt[2 * tid + 1];
      int s = a + bv;
#pragma unroll
      for (int o = 1; o < 64; o <<= 1) {
        int t2 = __shfl_up(s, o, 64);
        if ((int)tid >= o) s += t2;
      }
      int excl = s - (a + bv);
      soff[2 * tid] = excl;
      soff[2 * tid + 1] = excl + a;
      if (tid == 63) soff[CBLK] = s;
    }
    __syncthreads();
    m = soff[CBLK];
    for (int e = tid; e < CBLK * BCAP; e += 1024) {
      int j = e >> 5, s = e & (BCAP - 1);
      if (s < scnt[j]) keys[soff[j] + s] = bdata[((size_t)((b * CBLK + j) * CLS + (bc % CLS))) * BCAP + s];
    }
  } else {
    m = ccount[bc]; if (m > CAND_CAP) m = CAND_CAP;
    for (int i = tid; i < m; i += 1024) keys[i] = cand[(size_t)bc * CAND_CAP + i];
  }
  int nsort = 1024; while (nsort < m) nsort <<= 1;
  for (int i = m + tid; i < nsort; i += 1024) keys[i] = 0ULL;
  __syncthreads();

  if (nsort <= 1024) {
    u64 key = keys[tid];
    __syncthreads();
    for (int k2 = 2; k2 <= 1024; k2 <<= 1) {
      for (int j = k2 >> 1; j > 0; j >>= 1) {
        u64 other;
        if (j >= 64) {
          keys[tid] = key; __syncthreads();
          other = keys[tid ^ j]; __syncthreads();
        } else {
          other = shflx64(key, j);
        }
        bool keepmax = (((tid & k2) == 0) == ((tid & j) == 0));
        key = keepmax ? (key >= other ? key : other) : (key <= other ? key : other);
      }
    }
    keys[tid] = key;
    __syncthreads();
  } else {
    for (int k2 = 2; k2 <= nsort; k2 <<= 1) {
      for (int j = k2 >> 1; j > 0; j >>= 1) {
        for (int i = tid; i < nsort; i += 1024) {
          int ij = i ^ j;
          if (ij > i) {
            u64 a = keys[i], bv = keys[ij];
            bool up = ((i & k2) == 0);
            if (up ? (a < bv) : (a > bv)) { keys[i] = bv; keys[ij] = a; }
          }
        }
        __syncthreads();
      }
    }
  }

  // write sorted keys, fetch boxes, init keep-words from validity
  if (tid < 512) {
    u64 key = (tid < K_PRE) ? keys[tid] : 0ULL;
    skey[(size_t)bc * 512 + tid] = key;
    float sc = __uint_as_float((unsigned)(key >> 32));
    unsigned anchor = 0xFFFFFFFFu - (unsigned)(key & 0xFFFFFFFFu);
    bool val = (tid < K_PRE) && (sc > SCORE_TH);
    if (!val || anchor >= NN) anchor = 0;
    float4 bx = *(const float4*)(boxes + ((size_t)b * NN + anchor) * 4);
    if (tid < K_PRE) {
      sboxg[(size_t)bc * K_PRE + tid] = bx;
      sarg[(size_t)bc * K_PRE + tid] = fmaxf(bx.z - bx.x, 0.0f) * fmaxf(bx.w - bx.y, 0.0f);
    }
    u64 bm = __ballot(val);
    if ((tid & 63) == 0) keepi[bc * 8 + (tid >> 6)] = bm;
  }
}

// ---- bitmatrix: grid (4, 160); block handles 128 rows x 512 cols; coalesced word stores ----
__global__ __launch_bounds__(1024) void k_bitmat(const float4* __restrict__ sboxg,
                                                 const float* __restrict__ sarg, u64* __restrict__ sup) {
  __shared__ float4 rbox[128];
  __shared__ float rar[128];
  int bc = blockIdx.y, rch = blockIdx.x;
  int tid = threadIdx.x;
  int half = tid >> 9;
  int j = tid & 511;
  int w = (tid >> 6) & 7;
  int lane = tid & 63;
  if (tid < 128) {
    int r = rch * 128 + tid;
    int rc = r < K_PRE ? r : 0;
    rbox[tid] = sboxg[(size_t)bc * K_PRE + rc];
    rar[tid] = sarg[(size_t)bc * K_PRE + rc];
  }
  __syncthreads();
  int jc = j < K_PRE ? j : 0;
  float4 bj = sboxg[(size_t)bc * K_PRE + jc];
  float aj = sarg[(size_t)bc * K_PRE + jc];
  bool jval = j < K_PRE;
  int i0 = rch * 128 + half * 64;
  u64 myword = 0;
  for (int k = 0; k < 64; ++k) {
    int i = i0 + k;
    float4 bi = rbox[half * 64 + k];
    float ai = rar[half * 64 + k];
    float iw = fmaxf(fminf(bi.z, bj.z) - fmaxf(bi.x, bj.x), 0.0f);
    float ih = fmaxf(fminf(bi.w, bj.w) - fmaxf(bi.y, bj.y), 0.0f);
    float inter = iw * ih;
    float denom = fmaxf(ai + aj - inter, 1e-8f);
    bool pred = jval && (j > i) && (inter / denom > NMS_THR);
    u64 msk = __ballot(pred);
    if (k == lane) myword = msk;
  }
  int i = i0 + lane;
  if (i < K_PRE) sup[(size_t)bc * 4096 + w * 512 + i] = myword;  // coalesced per wave
}

// ---- sweep: stage sup slice to LDS, serial greedy, rank+compact ----
#define SUPW 508
__global__ __launch_bounds__(512) void k_sweep(const u64* __restrict__ sup, const u64* __restrict__ keepi,
                                               const u64* __restrict__ skey, u64* __restrict__ cselk,
                                               int* __restrict__ csela, int* __restrict__ ksel) {
  __shared__ u64 lsup[8 * SUPW];  // ~32.5KB; banks (24w+2i)%32 -> 2-way (free)
  __shared__ u64 keepw[8];
  int bc = blockIdx.x;
  int c = bc % CLS;
  int tid = threadIdx.x;
  for (int idx = tid; idx < 4096; idx += 512) {
    int w = idx >> 9, i = idx & 511;
    if (i < K_PRE) lsup[w * SUPW + i] = sup[(size_t)bc * 4096 + idx];
  }
  if (tid < 8) keepw[tid] = keepi[bc * 8 + tid];
  __syncthreads();
  if (tid < 64) {
    u64 kw = (tid < 8) ? keepw[tid] : 0ULL;
    u64 row = (tid < 8) ? lsup[tid * SUPW] : 0ULL;
    for (int i = 0; i < K_PRE; ++i) {
      u64 nrow = (tid < 8 && i + 1 < K_PRE) ? lsup[tid * SUPW + i + 1] : 0ULL;
      int owner = i >> 6;
      unsigned bit = (unsigned)((kw >> (i & 63)) & 1ULL);
      bit = (unsigned)__shfl((int)bit, owner, 64);
      u64 msk = 0ULL - (u64)bit;
      kw &= ~(row & msk);
      row = nrow;
    }
    if (tid < 8) keepw[tid] = kw;
    int cnt = (tid < 8) ? __popcll(kw) : 0;
    cnt += __shfl_xor(cnt, 1, 64);
    cnt += __shfl_xor(cnt, 2, 64);
    cnt += __shfl_xor(cnt, 4, 64);
    if (tid == 0) ksel[bc] = cnt > MAXDET ? MAXDET : cnt;
  }
  __syncthreads();
  if (tid < K_PRE) {
    int w = tid >> 6, bpos = tid & 63;
    u64 kw = keepw[w];
    if ((kw >> bpos) & 1ULL) {
      int rank = 0;
      for (int ww = 0; ww < w; ++ww) rank += __popcll(keepw[ww]);
      rank += __popcll(kw & ((1ULL << bpos) - 1ULL));
      if (rank < MAXDET) {
        u64 key = skey[(size_t)bc * 512 + tid];
        float sc = __uint_as_float((unsigned)(key >> 32));
        unsigned anchor = 0xFFFFFFFFu - (unsigned)(key & 0xFFFFFFFFu);
        if (anchor >= NN) anchor = 0;
        unsigned flat = (unsigned)(c * K_PRE + tid);
        cselk[(size_t)bc * MAXDET + rank] = ((u64)__float_as_uint(sc) << 32) | (u64)(0xFFFFFFFFu - flat);
        csela[(size_t)bc * MAXDET + rank] = (int)anchor;
      }
    }
  }
}

// ---- per-image: top-48-per-class truncate + 1024 bitonic -> exact global top-300 ----
// exactness: any excluded element sits at position >=48 of its list, whose 49th key
// must be < sorted[299] (checked); then >=300 keys exceed it -> not in top-300.
// fallback (check fails): the old serial tournament, known-correct.
__global__ __launch_bounds__(1024) void k_out(const float* __restrict__ boxes, const u64* __restrict__ cselk,
                                              const u64* __restrict__ skeyg, const int* __restrict__ csela,
                                              const int* __restrict__ ksel, float* __restrict__ out) {
  __shared__ u64 skeym[CLS][MAXDET];  // 48KB
  __shared__ int skc[CLS];
  __shared__ u64 carr[1024];          // 8KB: candidates + bitonic exchange buffer
  __shared__ int scond;
  __shared__ u64 sT;
  __shared__ int winc[MAXDET];
  __shared__ float winsc[MAXDET];
  int b = blockIdx.x, tid = threadIdx.x;
  if (tid < CLS) skc[tid] = ksel[b * CLS + tid];
  if (tid == 0) scond = 1;
  __syncthreads();
  for (int t = tid; t < CLS * MAXDET; t += 1024) {
    int c = t / MAXDET, p = t % MAXDET;
    skeym[c][p] = (p < skc[c]) ? cselk[(size_t)(b * CLS + c) * MAXDET + p] : 0ULL;
  }
  __syncthreads();
  // top-48 of each class -> 960 candidates, pad to 1024
  {
    u64 v = 0ULL;
    if (tid < CLS * 48) {
      int c = tid / 48, p = tid % 48;
      if (p < skc[c]) v = skeym[c][p];
    }
    carr[tid] = v;
  }
  __syncthreads();
  // in-register bitonic 1024, descending (shfl_xor j<64, LDS exchange j>=64)
  {
    u64 key = carr[tid];
    __syncthreads();
    for (int k2 = 2; k2 <= 1024; k2 <<= 1) {
      for (int j = k2 >> 1; j > 0; j >>= 1) {
        u64 other;
        if (j >= 64) {
          carr[tid] = key; __syncthreads();
          other = carr[tid ^ j]; __syncthreads();
        } else {
          other = shflx64(key, j);
        }
        bool keepmax = (((tid & k2) == 0) == ((tid & j) == 0));
        key = keepmax ? (key >= other ? key : other) : (key <= other ? key : other);
      }
    }
    carr[tid] = key;
    __syncthreads();
  }
  if (tid == 0) sT = carr[MAXDET - 1];
  __syncthreads();
  if (tid < CLS) {
    if (skc[tid] > 48 && skeym[tid][48] >= sT) atomicAnd(&scond, 0);
  }
  __syncthreads();

  if (scond) {
    for (int i = tid; i < MAXDET; i += 1024) {
      u64 kk = carr[i];
      float4 bx; float sc, lb;
      if (kk == 0ULL) {
        bx = make_float4(-1.f, -1.f, -1.f, -1.f); sc = -1.f; lb = -1.f;
      } else {
        unsigned flat = 0xFFFFFFFFu - (unsigned)(kk & 0xFFFFFFFFu);
        int c = flat / K_PRE, pos = flat % K_PRE;
        u64 sk = skeyg[(size_t)(b * CLS + c) * 512 + pos];
        unsigned anchor = 0xFFFFFFFFu - (unsigned)(sk & 0xFFFFFFFFu);
        if (anchor >= NN) anchor = 0;
        bx = *(const float4*)(boxes + ((size_t)b * NN + anchor) * 4);
        sc = __uint_as_float((unsigned)(kk >> 32));
        lb = (float)(c - 1);  // reference: out_labels = fl - 1
      }
      *(float4*)(out + ((size_t)b * MAXDET + i) * 4) = bx;
      out[BB * MAXDET * 4 + b * MAXDET + i] = sc;
      out[BB * MAXDET * 4 + BB * MAXDET + b * MAXDET + i] = lb;
    }
    return;
  }

  // ---- fallback: serial tournament (rare; exact) ----
  if (tid < 64) {
    int lane = tid;
    u64 cur = 0, nxt = 0; int p = 0, kc = 0;
    if (lane < CLS) {
      kc = skc[lane];
      cur = kc > 0 ? skeym[lane][0] : 0ULL;
      nxt = kc > 1 ? skeym[lane][1] : 0ULL;
    }
    for (int i = 0; i < MAXDET; ++i) {
      u64 mx = cur;
#pragma unroll
      for (int off = 16; off >= 1; off >>= 1) {
        unsigned hi = __shfl_xor((int)(unsigned)(mx >> 32), off, 32);
        unsigned lo = __shfl_xor((int)(unsigned)(mx & 0xFFFFFFFFu), off, 32);
        u64 o = ((u64)hi << 32) | lo;
        if (o > mx) mx = o;
      }
      if (mx != 0ULL && cur == mx) {
        winc[i] = (lane << 16) | p;
        winsc[i] = __uint_as_float((unsigned)(mx >> 32));
        ++p;
        cur = nxt;
        nxt = (p + 1 < kc) ? skeym[lane][p + 1] : 0ULL;
      }
      if (mx == 0ULL && lane == 0) winc[i] = -1;
    }
  }
  __syncthreads();
  for (int i = tid; i < MAXDET; i += 1024) {
    int wc = winc[i];
    float4 bx; float sc, lb;
    if (wc < 0) {
      bx = make_float4(-1.f, -1.f, -1.f, -1.f); sc = -1.f; lb = -1.f;
    } else {
      int c = wc >> 16, p = wc & 0xFFFF;
      int anchor = csela[(size_t)(b * CLS + c) * MAXDET + p];
      bx = *(const float4*)(boxes + ((size_t)b * NN + anchor) * 4);
      sc = winsc[i];
      lb = (float)(c - 1);
    }
    *(float4*)(out + ((size_t)b * MAXDET + i) * 4) = bx;
    out[BB * MAXDET * 4 + b * MAXDET + i] = sc;
    out[BB * MAXDET * 4 + BB * MAXDET + b * MAXDET + i] = lb;
  }
}

extern "C" void kernel_launch(void* const* d_in, const int* in_sizes, int n_in,
                              void* d_out, int out_size, void* d_ws, size_t ws_size,
                              hipStream_t stream) {
  (void)in_sizes; (void)n_in; (void)out_size; (void)ws_size;
  const float* boxes = (const float*)d_in[0];
  const float* cls = (const float*)d_in[1];
  float* out = (float*)d_out;
  char* ws = (char*)d_ws;
  int* hist   = (int*)(ws + HIST_OFF);
  int* thr    = (int*)(ws + THR_OFF);
  int* ccount = (int*)(ws + CCNT_OFF);
  int* ksel   = (int*)(ws + KSEL_OFF);
  u64* cand   = (u64*)(ws + CAND_OFF);
  u64* cselk  = (u64*)(ws + CSELK_OFF);
  int* csela  = (int*)(ws + CSELA_OFF);
  int* bcnt   = (int*)(ws + BCNT_OFF);
  u64* bdata  = (u64*)(ws + BDATA_OFF);
  u64* skey   = (u64*)(ws + SKEY_OFF);
  float4* sboxg = (float4*)(ws + SBOX_OFF);
  float* sarg = (float*)(ws + SAR_OFF);
  u64* keepi  = (u64*)(ws + KEEPI_OFF);
  u64* sup    = cand;  // cand region reused as sup after k_sortgather

  hipMemsetAsync(ws, 0, ZERO_BYTES, stream);
  k_collect<<<dim3(CBLK, BB), CTHR, 0, stream>>>(cls, bcnt, bdata);
  k_sum<<<dim3(CLS, BB), 64, 0, stream>>>(bcnt, ccount);
  k_fb_hist<<<dim3(SLABS, BB), 256, 0, stream>>>(cls, ccount, hist);
  k_fb_thr<<<1, 256, 0, stream>>>(hist, thr, ccount);
  k_fb_collect<<<dim3(SLABS, BB), 256, 0, stream>>>(cls, thr, ccount, cand);
  k_sortgather<<<BB * CLS, 1024, 0, stream>>>(boxes, ccount, thr, bcnt, bdata, cand,
                                              skey, sboxg, sarg, keepi);
  k_bitmat<<<dim3(4, BB * CLS), 1024, 0, stream>>>(sboxg, sarg, sup);
  k_sweep<<<BB * CLS, 512, 0, stream>>>(sup, keepi, skey, cselk, csela, ksel);
  k_out<<<BB, 1024, 0, stream>>>(boxes, cselk, skey, csela, ksel, out);
}

// Round 8
// 147.260 us; speedup vs baseline: 4.9983x; 1.0778x over previous
//
#include <hip/hip_runtime.h>
#include <stdint.h>

typedef unsigned long long u64;

#define BB 8
#define NN 200000
#define CLS 20
#define K_PRE 500
#define MAXDET 300
#define SCORE_TH 0.05f
#define NMS_THR 0.5f

#define NBINS 512
#define CAND_CAP 4096

// fast path: fixed conservative collect threshold (uniform scores -> ~842/class >> 500)
// exactness for arbitrary inputs preserved by the IN-BLOCK histogram fallback in k_sortgather.
#define T_COL 0.996f

// collect geometry
#define CBLK 128
#define CTHR 256
#define IMG_F4 1000000
#define ITERS 4
#define BCAP 32

static constexpr float BINSCALE = (float)NBINS / 0.95f;

// ws layout (bytes) -- NO region is read before being written within one launch sequence,
// so no memset node is needed (graph has exactly 5 kernel nodes).
#define BCNT_OFF 0              // 1024*20*4 = 81920
#define BDATA_OFF 81920         // 1024*20*32*8 = 5242880 -> 5324800
#define SKEY_OFF 5324800        // 160*512*8 = 655360 -> 5980160
#define SBOX_OFF 5980160        // 160*500*16 = 1280000 -> 7260160
#define SAR_OFF  7260160        // 160*500*4 = 320000 -> 7580160
#define KEEPI_OFF 7580160       // 160*8*8 = 10240 -> 7590400
#define SUP_OFF  7590400        // 160*4096*8 = 5242880 -> 12833280
#define CSELK_OFF 12833280      // 160*300*8 = 384000 -> 13217280
#define CSELA_OFF 13217280      // 160*300*4 = 192000 -> 13409280
#define KSEL_OFF 13409280       // 640 -> 13409920

__device__ __forceinline__ int score_bin(float s) {
  int b = (int)((s - SCORE_TH) * BINSCALE);
  return b < 0 ? 0 : (b > NBINS - 1 ? NBINS - 1 : b);
}

__device__ __forceinline__ u64 shflx64(u64 v, int mask) {
  int hi = __shfl_xor((int)(unsigned)(v >> 32), mask, 64);
  int lo = __shfl_xor((int)(unsigned)(v & 0xFFFFFFFFu), mask, 64);
  return ((u64)(unsigned)hi << 32) | (unsigned)lo;
}

// ---- streaming pass: zero global atomics, LDS staging, per-block output region ----
__global__ __launch_bounds__(256) void k_collect(const float* __restrict__ cls,
                                                 int* __restrict__ bcnt, u64* __restrict__ bdata) {
  __shared__ u64 ldata[CLS][BCAP];
  __shared__ int lcnt[CLS];
  int tid = threadIdx.x;
  if (tid < CLS) lcnt[tid] = 0;
  __syncthreads();
  int blk = blockIdx.x, b = blockIdx.y;
  const float4* p = (const float4*)(cls + (size_t)b * IMG_F4 * 4);
  int base0 = blk * (ITERS * 8 * CTHR);
  bool full = (base0 + ITERS * 8 * CTHR) <= IMG_F4;

#define PROC(v, fidx) { \
    float m4_ = fmaxf(fmaxf((v).x, (v).y), fmaxf((v).z, (v).w)); \
    if (m4_ > T_COL) { \
      float vv_[4] = {(v).x, (v).y, (v).z, (v).w}; \
      _Pragma("unroll") \
      for (int e_ = 0; e_ < 4; ++e_) { \
        if (vv_[e_] > T_COL) { \
          int g_ = (fidx) * 4 + e_; \
          int c_ = g_ % CLS, a_ = g_ / CLS; \
          int li_ = atomicAdd(&lcnt[c_], 1); \
          if (li_ < BCAP) \
            ldata[c_][li_] = ((u64)__float_as_uint(vv_[e_]) << 32) | (u64)(0xFFFFFFFFu - (unsigned)a_); \
        } \
      } \
    } }

  for (int it = 0; it < ITERS; ++it) {
    int i0 = base0 + it * (8 * CTHR) + tid;
    if (full) {
      float4 v0 = p[i0];
      float4 v1 = p[i0 + 1 * CTHR];
      float4 v2 = p[i0 + 2 * CTHR];
      float4 v3 = p[i0 + 3 * CTHR];
      float4 v4 = p[i0 + 4 * CTHR];
      float4 v5 = p[i0 + 5 * CTHR];
      float4 v6 = p[i0 + 6 * CTHR];
      float4 v7 = p[i0 + 7 * CTHR];
      PROC(v0, i0);
      PROC(v1, i0 + 1 * CTHR);
      PROC(v2, i0 + 2 * CTHR);
      PROC(v3, i0 + 3 * CTHR);
      PROC(v4, i0 + 4 * CTHR);
      PROC(v5, i0 + 5 * CTHR);
      PROC(v6, i0 + 6 * CTHR);
      PROC(v7, i0 + 7 * CTHR);
    } else {
      for (int k = 0; k < 8; ++k) {
        int idx = i0 + k * CTHR;
        if (idx < IMG_F4) { float4 v = p[idx]; PROC(v, idx); }
      }
    }
  }
#undef PROC
  __syncthreads();
  int w = tid >> 6, lane = tid & 63;
  int gblk = b * CBLK + blk;
  for (int c = w; c < CLS; c += 4) {
    int cnt = lcnt[c];
    if (lane == 0) bcnt[gblk * CLS + c] = cnt;   // real count (may exceed BCAP -> fallback)
    int ns = cnt < BCAP ? cnt : BCAP;
    if (lane < ns) bdata[((size_t)(gblk * CLS + c)) * BCAP + lane] = ldata[c][lane];
  }
}

// ---- per-(b,c): validity check + gather (or in-block fallback) + exact top-500 sort ----
__global__ __launch_bounds__(1024) void k_sortgather(const float* __restrict__ boxes,
                                                     const float* __restrict__ cls,
                                                     const int* __restrict__ bcnt, const u64* __restrict__ bdata,
                                                     u64* __restrict__ skey, float4* __restrict__ sboxg,
                                                     float* __restrict__ sarg, u64* __restrict__ keepi) {
  __shared__ u64 keys[CAND_CAP];       // 32KB
  __shared__ int scnt[CBLK], soff[CBLK + 1];
  __shared__ int lh[NBINS];            // 2KB, fallback histogram
  __shared__ int sflag, sbin, scount;
  int bc = blockIdx.x;
  int b = bc / CLS, c = bc % CLS;
  int tid = threadIdx.x;
  if (tid == 0) { sflag = 0; scount = 0; }
  __syncthreads();
  if (tid < CBLK) {
    int v = bcnt[(b * CBLK + tid) * CLS + c];
    scnt[tid] = v;
    if (v > BCAP) atomicOr(&sflag, 1);
  }
  __syncthreads();
  // single-wave exclusive scan of 128 counts (2 per lane)
  if (tid < 64) {
    int a = scnt[2 * tid], bv = scnt[2 * tid + 1];
    int s = a + bv;
#pragma unroll
    for (int o = 1; o < 64; o <<= 1) {
      int t2 = __shfl_up(s, o, 64);
      if ((int)tid >= o) s += t2;
    }
    int excl = s - (a + bv);
    soff[2 * tid] = excl;
    soff[2 * tid + 1] = excl + a;
    if (tid == 63) soff[CBLK] = s;
  }
  __syncthreads();
  int total = soff[CBLK];
  bool fallback = (sflag != 0) || (total > CAND_CAP) || (total < K_PRE);
  int m;
  if (!fallback) {
    m = total;
    for (int e = tid; e < CBLK * BCAP; e += 1024) {
      int j = e >> 5, s = e & (BCAP - 1);
      if (s < scnt[j]) keys[soff[j] + s] = bdata[((size_t)((b * CBLK + j) * CLS + c)) * BCAP + s];
    }
  } else {
    // in-block exact fallback: histogram over this (b,c) column, threshold, collect.
    for (int i = tid; i < NBINS; i += 1024) lh[i] = 0;
    __syncthreads();
    for (int a = tid; a < NN; a += 1024) {
      float s = cls[((size_t)b * NN + a) * CLS + c];
      if (s > SCORE_TH) atomicAdd(&lh[score_bin(s)], 1);
    }
    __syncthreads();
    if (tid == 0) {
      int sum = 0, bin = 0;
      for (int i = NBINS - 1; i >= 0; --i) {
        sum += lh[i];
        if (sum >= K_PRE) { bin = i; break; }
      }
      sbin = bin;
    }
    __syncthreads();
    int bin = sbin;
    for (int a = tid; a < NN; a += 1024) {
      float s = cls[((size_t)b * NN + a) * CLS + c];
      if (s > SCORE_TH && score_bin(s) >= bin) {
        int pos = atomicAdd(&scount, 1);
        if (pos < CAND_CAP)
          keys[pos] = ((u64)__float_as_uint(s) << 32) | (u64)(0xFFFFFFFFu - (unsigned)a);
      }
    }
    __syncthreads();
    m = scount; if (m > CAND_CAP) m = CAND_CAP;
  }
  int nsort = 1024; while (nsort < m) nsort <<= 1;
  for (int i = m + tid; i < nsort; i += 1024) keys[i] = 0ULL;
  __syncthreads();

  if (nsort <= 1024) {
    // in-register bitonic, descending; shfl_xor for j<64, LDS exchange for j>=64
    u64 key = keys[tid];
    __syncthreads();
    for (int k2 = 2; k2 <= 1024; k2 <<= 1) {
      for (int j = k2 >> 1; j > 0; j >>= 1) {
        u64 other;
        if (j >= 64) {
          keys[tid] = key; __syncthreads();
          other = keys[tid ^ j]; __syncthreads();
        } else {
          other = shflx64(key, j);
        }
        bool keepmax = (((tid & k2) == 0) == ((tid & j) == 0));
        key = keepmax ? (key >= other ? key : other) : (key <= other ? key : other);
      }
    }
    keys[tid] = key;
    __syncthreads();
  } else {
    // LDS bitonic up to 4096 (rare)
    for (int k2 = 2; k2 <= nsort; k2 <<= 1) {
      for (int j = k2 >> 1; j > 0; j >>= 1) {
        for (int i = tid; i < nsort; i += 1024) {
          int ij = i ^ j;
          if (ij > i) {
            u64 a = keys[i], bv = keys[ij];
            bool up = ((i & k2) == 0);
            if (up ? (a < bv) : (a > bv)) { keys[i] = bv; keys[ij] = a; }
          }
        }
        __syncthreads();
      }
    }
  }

  // write sorted keys, fetch boxes, init keep-words from validity
  if (tid < 512) {
    u64 key = (tid < K_PRE) ? keys[tid] : 0ULL;
    skey[(size_t)bc * 512 + tid] = key;
    float sc = __uint_as_float((unsigned)(key >> 32));
    unsigned anchor = 0xFFFFFFFFu - (unsigned)(key & 0xFFFFFFFFu);
    bool val = (tid < K_PRE) && (sc > SCORE_TH);
    if (!val || anchor >= NN) anchor = 0;
    float4 bx = *(const float4*)(boxes + ((size_t)b * NN + anchor) * 4);
    if (tid < K_PRE) {
      sboxg[(size_t)bc * K_PRE + tid] = bx;
      sarg[(size_t)bc * K_PRE + tid] = fmaxf(bx.z - bx.x, 0.0f) * fmaxf(bx.w - bx.y, 0.0f);
    }
    u64 bm = __ballot(val);
    if ((tid & 63) == 0) keepi[bc * 8 + (tid >> 6)] = bm;
  }
}

// ---- bitmatrix: grid (4, 160); block handles 128 rows x 512 cols; coalesced word stores ----
__global__ __launch_bounds__(1024) void k_bitmat(const float4* __restrict__ sboxg,
                                                 const float* __restrict__ sarg, u64* __restrict__ sup) {
  __shared__ float4 rbox[128];
  __shared__ float rar[128];
  int bc = blockIdx.y, rch = blockIdx.x;
  int tid = threadIdx.x;
  int half = tid >> 9;
  int j = tid & 511;
  int w = (tid >> 6) & 7;
  int lane = tid & 63;
  if (tid < 128) {
    int r = rch * 128 + tid;
    int rc = r < K_PRE ? r : 0;
    rbox[tid] = sboxg[(size_t)bc * K_PRE + rc];
    rar[tid] = sarg[(size_t)bc * K_PRE + rc];
  }
  __syncthreads();
  int jc = j < K_PRE ? j : 0;
  float4 bj = sboxg[(size_t)bc * K_PRE + jc];
  float aj = sarg[(size_t)bc * K_PRE + jc];
  bool jval = j < K_PRE;
  int i0 = rch * 128 + half * 64;
  u64 myword = 0;
  for (int k = 0; k < 64; ++k) {
    int i = i0 + k;
    float4 bi = rbox[half * 64 + k];
    float ai = rar[half * 64 + k];
    float iw = fmaxf(fminf(bi.z, bj.z) - fmaxf(bi.x, bj.x), 0.0f);
    float ih = fmaxf(fminf(bi.w, bj.w) - fmaxf(bi.y, bj.y), 0.0f);
    float inter = iw * ih;
    float denom = fmaxf(ai + aj - inter, 1e-8f);
    bool pred = jval && (j > i) && (inter / denom > NMS_THR);
    u64 msk = __ballot(pred);
    if (k == lane) myword = msk;
  }
  int i = i0 + lane;
  if (i < K_PRE) sup[(size_t)bc * 4096 + w * 512 + i] = myword;  // coalesced per wave
}

// ---- sweep: stage sup slice to LDS, serial greedy, rank+compact ----
#define SUPW 508
__global__ __launch_bounds__(512) void k_sweep(const u64* __restrict__ sup, const u64* __restrict__ keepi,
                                               const u64* __restrict__ skey, u64* __restrict__ cselk,
                                               int* __restrict__ csela, int* __restrict__ ksel) {
  __shared__ u64 lsup[8 * SUPW];  // ~32.5KB; banks (24w+2i)%32 -> 2-way (free)
  __shared__ u64 keepw[8];
  int bc = blockIdx.x;
  int c = bc % CLS;
  int tid = threadIdx.x;
  for (int idx = tid; idx < 4096; idx += 512) {
    int w = idx >> 9, i = idx & 511;
    if (i < K_PRE) lsup[w * SUPW + i] = sup[(size_t)bc * 4096 + idx];
  }
  if (tid < 8) keepw[tid] = keepi[bc * 8 + tid];
  __syncthreads();
  if (tid < 64) {
    u64 kw = (tid < 8) ? keepw[tid] : 0ULL;
    u64 row = (tid < 8) ? lsup[tid * SUPW] : 0ULL;
    for (int i = 0; i < K_PRE; ++i) {
      u64 nrow = (tid < 8 && i + 1 < K_PRE) ? lsup[tid * SUPW + i + 1] : 0ULL;
      int owner = i >> 6;
      unsigned bit = (unsigned)((kw >> (i & 63)) & 1ULL);
      bit = (unsigned)__shfl((int)bit, owner, 64);
      u64 msk = 0ULL - (u64)bit;
      kw &= ~(row & msk);
      row = nrow;
    }
    if (tid < 8) keepw[tid] = kw;
    int cnt = (tid < 8) ? __popcll(kw) : 0;
    cnt += __shfl_xor(cnt, 1, 64);
    cnt += __shfl_xor(cnt, 2, 64);
    cnt += __shfl_xor(cnt, 4, 64);
    if (tid == 0) ksel[bc] = cnt > MAXDET ? MAXDET : cnt;
  }
  __syncthreads();
  if (tid < K_PRE) {
    int w = tid >> 6, bpos = tid & 63;
    u64 kw = keepw[w];
    if ((kw >> bpos) & 1ULL) {
      int rank = 0;
      for (int ww = 0; ww < w; ++ww) rank += __popcll(keepw[ww]);
      rank += __popcll(kw & ((1ULL << bpos) - 1ULL));
      if (rank < MAXDET) {
        u64 key = skey[(size_t)bc * 512 + tid];
        float sc = __uint_as_float((unsigned)(key >> 32));
        unsigned anchor = 0xFFFFFFFFu - (unsigned)(key & 0xFFFFFFFFu);
        if (anchor >= NN) anchor = 0;
        unsigned flat = (unsigned)(c * K_PRE + tid);
        cselk[(size_t)bc * MAXDET + rank] = ((u64)__float_as_uint(sc) << 32) | (u64)(0xFFFFFFFFu - flat);
        csela[(size_t)bc * MAXDET + rank] = (int)anchor;
      }
    }
  }
}

// ---- per-image: top-48-per-class truncate + 1024 bitonic -> exact global top-300 ----
// exactness: any excluded element sits at position >=48 of its list, whose 49th key
// must be < sorted[299] (checked); then >=300 keys exceed it -> not in top-300.
// fallback (check fails): serial tournament, known-correct.
__global__ __launch_bounds__(1024) void k_out(const float* __restrict__ boxes, const u64* __restrict__ cselk,
                                              const u64* __restrict__ skeyg, const int* __restrict__ csela,
                                              const int* __restrict__ ksel, float* __restrict__ out) {
  __shared__ u64 skeym[CLS][MAXDET];  // 48KB
  __shared__ int skc[CLS];
  __shared__ u64 carr[1024];          // 8KB: candidates + bitonic exchange buffer
  __shared__ int scond;
  __shared__ u64 sT;
  __shared__ int winc[MAXDET];
  __shared__ float winsc[MAXDET];
  int b = blockIdx.x, tid = threadIdx.x;
  if (tid < CLS) skc[tid] = ksel[b * CLS + tid];
  if (tid == 0) scond = 1;
  __syncthreads();
  for (int t = tid; t < CLS * MAXDET; t += 1024) {
    int c = t / MAXDET, p = t % MAXDET;
    skeym[c][p] = (p < skc[c]) ? cselk[(size_t)(b * CLS + c) * MAXDET + p] : 0ULL;
  }
  __syncthreads();
  {
    u64 v = 0ULL;
    if (tid < CLS * 48) {
      int c = tid / 48, p = tid % 48;
      if (p < skc[c]) v = skeym[c][p];
    }
    carr[tid] = v;
  }
  __syncthreads();
  {
    u64 key = carr[tid];
    __syncthreads();
    for (int k2 = 2; k2 <= 1024; k2 <<= 1) {
      for (int j = k2 >> 1; j > 0; j >>= 1) {
        u64 other;
        if (j >= 64) {
          carr[tid] = key; __syncthreads();
          other = carr[tid ^ j]; __syncthreads();
        } else {
          other = shflx64(key, j);
        }
        bool keepmax = (((tid & k2) == 0) == ((tid & j) == 0));
        key = keepmax ? (key >= other ? key : other) : (key <= other ? key : other);
      }
    }
    carr[tid] = key;
    __syncthreads();
  }
  if (tid == 0) sT = carr[MAXDET - 1];
  __syncthreads();
  if (tid < CLS) {
    if (skc[tid] > 48 && skeym[tid][48] >= sT) atomicAnd(&scond, 0);
  }
  __syncthreads();

  if (scond) {
    for (int i = tid; i < MAXDET; i += 1024) {
      u64 kk = carr[i];
      float4 bx; float sc, lb;
      if (kk == 0ULL) {
        bx = make_float4(-1.f, -1.f, -1.f, -1.f); sc = -1.f; lb = -1.f;
      } else {
        unsigned flat = 0xFFFFFFFFu - (unsigned)(kk & 0xFFFFFFFFu);
        int c = flat / K_PRE, pos = flat % K_PRE;
        u64 sk = skeyg[(size_t)(b * CLS + c) * 512 + pos];
        unsigned anchor = 0xFFFFFFFFu - (unsigned)(sk & 0xFFFFFFFFu);
        if (anchor >= NN) anchor = 0;
        bx = *(const float4*)(boxes + ((size_t)b * NN + anchor) * 4);
        sc = __uint_as_float((unsigned)(kk >> 32));
        lb = (float)(c - 1);  // reference: out_labels = fl - 1
      }
      *(float4*)(out + ((size_t)b * MAXDET + i) * 4) = bx;
      out[BB * MAXDET * 4 + b * MAXDET + i] = sc;
      out[BB * MAXDET * 4 + BB * MAXDET + b * MAXDET + i] = lb;
    }
    return;
  }

  // ---- fallback: serial tournament (rare; exact) ----
  if (tid < 64) {
    int lane = tid;
    u64 cur = 0, nxt = 0; int p = 0, kc = 0;
    if (lane < CLS) {
      kc = skc[lane];
      cur = kc > 0 ? skeym[lane][0] : 0ULL;
      nxt = kc > 1 ? skeym[lane][1] : 0ULL;
    }
    for (int i = 0; i < MAXDET; ++i) {
      u64 mx = cur;
#pragma unroll
      for (int off = 16; off >= 1; off >>= 1) {
        unsigned hi = __shfl_xor((int)(unsigned)(mx >> 32), off, 32);
        unsigned lo = __shfl_xor((int)(unsigned)(mx & 0xFFFFFFFFu), off, 32);
        u64 o = ((u64)hi << 32) | lo;
        if (o > mx) mx = o;
      }
      if (mx != 0ULL && cur == mx) {
        winc[i] = (lane << 16) | p;
        winsc[i] = __uint_as_float((unsigned)(mx >> 32));
        ++p;
        cur = nxt;
        nxt = (p + 1 < kc) ? skeym[lane][p + 1] : 0ULL;
      }
      if (mx == 0ULL && lane == 0) winc[i] = -1;
    }
  }
  __syncthreads();
  for (int i = tid; i < MAXDET; i += 1024) {
    int wc = winc[i];
    float4 bx; float sc, lb;
    if (wc < 0) {
      bx = make_float4(-1.f, -1.f, -1.f, -1.f); sc = -1.f; lb = -1.f;
    } else {
      int c = wc >> 16, p = wc & 0xFFFF;
      int anchor = csela[(size_t)(b * CLS + c) * MAXDET + p];
      bx = *(const float4*)(boxes + ((size_t)b * NN + anchor) * 4);
      sc = winsc[i];
      lb = (float)(c - 1);
    }
    *(float4*)(out + ((size_t)b * MAXDET + i) * 4) = bx;
    out[BB * MAXDET * 4 + b * MAXDET + i] = sc;
    out[BB * MAXDET * 4 + BB * MAXDET + b * MAXDET + i] = lb;
  }
}

extern "C" void kernel_launch(void* const* d_in, const int* in_sizes, int n_in,
                              void* d_out, int out_size, void* d_ws, size_t ws_size,
                              hipStream_t stream) {
  (void)in_sizes; (void)n_in; (void)out_size; (void)ws_size;
  const float* boxes = (const float*)d_in[0];
  const float* cls = (const float*)d_in[1];
  float* out = (float*)d_out;
  char* ws = (char*)d_ws;
  int* bcnt   = (int*)(ws + BCNT_OFF);
  u64* bdata  = (u64*)(ws + BDATA_OFF);
  u64* skey   = (u64*)(ws + SKEY_OFF);
  float4* sboxg = (float4*)(ws + SBOX_OFF);
  float* sarg = (float*)(ws + SAR_OFF);
  u64* keepi  = (u64*)(ws + KEEPI_OFF);
  u64* sup    = (u64*)(ws + SUP_OFF);
  u64* cselk  = (u64*)(ws + CSELK_OFF);
  int* csela  = (int*)(ws + CSELA_OFF);
  int* ksel   = (int*)(ws + KSEL_OFF);

  k_collect<<<dim3(CBLK, BB), CTHR, 0, stream>>>(cls, bcnt, bdata);
  k_sortgather<<<BB * CLS, 1024, 0, stream>>>(boxes, cls, bcnt, bdata, skey, sboxg, sarg, keepi);
  k_bitmat<<<dim3(4, BB * CLS), 1024, 0, stream>>>(sboxg, sarg, sup);
  k_sweep<<<BB * CLS, 512, 0, stream>>>(sup, keepi, skey, cselk, csela, ksel);
  k_out<<<BB, 1024, 0, stream>>>(boxes, cselk, skey, csela, ksel, out);
}